// Round 8
// baseline (2570.122 us; speedup 1.0000x reference)
//
#include <hip/hip_runtime.h>
#include <math.h>

#define N_NODES 200000
#define N_HE    100000
#define NNZ     1000000
#define F_RAW   29
#define N_MACRO 512
#define SLOPE   0.1f
#define L_TOTAL (N_NODES + N_HE)   // 300000 combined counters
#define NB_SCAN 293                // ceil(300000/1024)

__device__ __forceinline__ float lrelu(float v) { return v >= 0.f ? v : SLOPE * v; }
__device__ __forceinline__ float bf2f(unsigned short u) { return __uint_as_float(((unsigned)u) << 16); }
__device__ __forceinline__ unsigned short f2bf(float f) {
    unsigned u = __float_as_uint(f);
    unsigned r = u + 0x7FFFu + ((u >> 16) & 1u);   // RNE
    return (unsigned short)(r >> 16);
}

// ---------- fills ----------
__global__ __launch_bounds__(256) void fill_f32(float* p, long long n, float v) {
    long long i = (long long)blockIdx.x * blockDim.x + threadIdx.x;
    long long st = (long long)gridDim.x * blockDim.x;
    for (; i < n; i += st) p[i] = v;
}

__global__ __launch_bounds__(256) void k_ismacro(const int* __restrict__ mi,
                                                 float* __restrict__ ismacro, int* __restrict__ mcount) {
    int i = blockIdx.x * blockDim.x + threadIdx.x;
    if (i < N_MACRO) {
        ismacro[mi[i]] = 1.0f;
        atomicAdd(&mcount[mi[i]], 1);
    }
}

// ---------- va[k] = W1[k,:]·att[:64], va[32] = b1·att[:64] ----------
__global__ __launch_bounds__(64) void k_va(const float* __restrict__ W1, const float* __restrict__ b1,
                                           const float* __restrict__ att, float* __restrict__ va) {
    int t = threadIdx.x;
    if (t < 32) {
        float a = 0.f;
        for (int c = 0; c < 64; c++) a += W1[t * 64 + c] * att[c];
        va[t] = a;
    } else if (t == 32) {
        float a = 0.f;
        for (int c = 0; c < 64; c++) a += b1[c] * att[c];
        va[32] = a;
    }
}

// ---------- build h rows (32 bf16) + xn_att ----------
__global__ __launch_bounds__(256) void k_h(
    const float* __restrict__ x, const float* __restrict__ fp,
    const float* __restrict__ ismacro, const float* __restrict__ va,
    unsigned short* __restrict__ h, float* __restrict__ xn_att)
{
    const int lane = threadIdx.x & 63;
    const int half = lane >> 5, k = lane & 31;
    int wid = (blockIdx.x * blockDim.x + threadIdx.x) >> 6;
    int nw = (gridDim.x * blockDim.x) >> 6;
    float vak = va[k];
    float c0 = va[32];
    for (int base = wid * 2; base < N_NODES; base += nw * 2) {
        int n = base + half;
        float v;
        if (k < 29)       v = x[(size_t)n * F_RAW + k];
        else if (k == 29) v = fp[2 * n];
        else if (k == 30) v = fp[2 * n + 1];
        else              v = ismacro[n];
        h[(size_t)n * 32 + k] = f2bf(v);
        float r = v * vak;
        #pragma unroll
        for (int o = 16; o > 0; o >>= 1) r += __shfl_xor(r, o, 32);
        if (k == 0) xn_att[n] = r + c0;
    }
}

// ---------- counts + per-pin ranks (atomicAdd old value) ----------
__global__ __launch_bounds__(256) void k_count(
    const int* __restrict__ nidx, const int* __restrict__ hidx,
    int* __restrict__ cnt, int* __restrict__ rank_n, int* __restrict__ rank_e)
{
    int i = blockIdx.x * blockDim.x + threadIdx.x;
    int st = gridDim.x * blockDim.x;
    for (int p = i; p < NNZ; p += st) {
        rank_n[p] = atomicAdd(&cnt[nidx[p]], 1);
        rank_e[p] = atomicAdd(&cnt[N_NODES + hidx[p]], 1);
    }
}

// ---------- scan of cnt (length L_TOTAL) -> row_ptr ----------
__global__ __launch_bounds__(256) void k_scan1(const int* __restrict__ cnt,
                                               int* __restrict__ row_ptr, int* __restrict__ partials)
{
    __shared__ int sA[256], sB[256];
    const int t = threadIdx.x;
    const int base = blockIdx.x * 1024 + t * 4;
    int v0 = base + 0 < L_TOTAL ? cnt[base + 0] : 0;
    int v1 = base + 1 < L_TOTAL ? cnt[base + 1] : 0;
    int v2 = base + 2 < L_TOTAL ? cnt[base + 2] : 0;
    int v3 = base + 3 < L_TOTAL ? cnt[base + 3] : 0;
    sA[t] = v0 + v1 + v2 + v3;
    __syncthreads();
    int* src = sA; int* dst = sB;
    for (int off = 1; off < 256; off <<= 1) {
        int v = src[t];
        if (t >= off) v += src[t - off];
        dst[t] = v;
        __syncthreads();
        int* tmp = src; src = dst; dst = tmp;
    }
    int excl = t > 0 ? src[t - 1] : 0;
    if (base + 0 < L_TOTAL) row_ptr[base + 0] = excl;
    if (base + 1 < L_TOTAL) row_ptr[base + 1] = excl + v0;
    if (base + 2 < L_TOTAL) row_ptr[base + 2] = excl + v0 + v1;
    if (base + 3 < L_TOTAL) row_ptr[base + 3] = excl + v0 + v1 + v2;
    if (t == 255) partials[blockIdx.x] = src[255];
}

__global__ __launch_bounds__(512) void k_scan2(int* __restrict__ partials)
{
    __shared__ int sA[512], sB[512];
    const int t = threadIdx.x;
    sA[t] = t < NB_SCAN ? partials[t] : 0;
    __syncthreads();
    int* src = sA; int* dst = sB;
    for (int off = 1; off < 512; off <<= 1) {
        int v = src[t];
        if (t >= off) v += src[t - off];
        dst[t] = v;
        __syncthreads();
        int* tmp = src; src = dst; dst = tmp;
    }
    if (t < NB_SCAN) partials[t] = t > 0 ? src[t - 1] : 0;
    if (t == 0) partials[NB_SCAN] = src[511];
}

__global__ __launch_bounds__(256) void k_scan3(int* __restrict__ row_ptr, const int* __restrict__ partials)
{
    const int base = blockIdx.x * 1024 + threadIdx.x * 4;
    int add = partials[blockIdx.x];
    #pragma unroll
    for (int k = 0; k < 4; k++)
        if (base + k < L_TOTAL) row_ptr[base + k] += add;
    if (blockIdx.x == 0 && threadIdx.x == 0) row_ptr[L_TOTAL] = partials[NB_SCAN];
}

// ---------- atomic-free scatter: csr + bf16 pinf into he-slot order ----------
__global__ __launch_bounds__(256) void k_scatter(
    const int* __restrict__ nidx, const int* __restrict__ hidx,
    const int* __restrict__ row_ptr,
    const int* __restrict__ rank_n, const int* __restrict__ rank_e,
    const float4* __restrict__ pf4, int* __restrict__ csr, ushort4* __restrict__ pfh)
{
    int i = blockIdx.x * blockDim.x + threadIdx.x;
    int st = gridDim.x * blockDim.x;
    for (int p = i; p < NNZ; p += st) {
        int n = nidx[p], e = hidx[p];
        csr[row_ptr[n] + rank_n[p]] = e;
        int pe = row_ptr[N_NODES + e] + rank_e[p];  // absolute slot (>= NNZ)
        csr[pe] = n;
        float4 q = pf4[p];
        ushort4 r;
        r.x = f2bf(q.x); r.y = f2bf(q.y); r.z = f2bf(q.z); r.w = f2bf(q.w);
        pfh[pe - NNZ] = r;
    }
}

// ---------- he-side: gather bf16 h rows + coalesced bf16 pinf, matvec W1 ----------
__global__ __launch_bounds__(256) void k_he_agg(
    const int* __restrict__ row_ptr, const int* __restrict__ csr,
    const ushort4* __restrict__ pfh,
    const float* __restrict__ W1, const float* __restrict__ Wpin,
    const float* __restrict__ b1, const float* __restrict__ att,
    const unsigned short* __restrict__ h,
    unsigned short* __restrict__ e_feat, float* __restrict__ e_att)
{
    __shared__ float sW1[32 * 64];
    __shared__ float sWp[4 * 64];
    __shared__ float sb1[64];
    for (int i = threadIdx.x; i < 32 * 64; i += 256) sW1[i] = W1[i];
    for (int i = threadIdx.x; i < 4 * 64; i += 256) sWp[i] = Wpin[i];
    if (threadIdx.x < 64) sb1[threadIdx.x] = b1[threadIdx.x];
    __syncthreads();
    const int lane = threadIdx.x & 63;
    const int half = lane >> 5, k32 = lane & 31;
    float att2 = att[64 + lane];
    int wid = (blockIdx.x * blockDim.x + threadIdx.x) >> 6;
    int nw = (gridDim.x * blockDim.x) >> 6;
    for (int e = wid; e < N_HE; e += nw) {
        int start = row_ptr[N_NODES + e];
        int deg = row_ptr[N_NODES + e + 1] - start;
        // gather h rows: each half-wave loads one 64B bf16 row per step
        float hs = 0.f;
        for (int t0 = 0; t0 < deg; t0 += 8) {
            #pragma unroll
            for (int r = 0; r < 4; r++) {
                int t = t0 + 2 * r + half;
                if (t < deg) {
                    int n = csr[start + t];
                    hs += bf2f(h[(size_t)n * 32 + k32]);
                }
            }
        }
        hs += __shfl_xor(hs, 32, 64);
        // coalesced bf16 pinf sums
        float p0 = 0.f, p1 = 0.f, p2 = 0.f, p3 = 0.f;
        for (int t = lane; t < deg; t += 64) {
            ushort4 r = pfh[start - NNZ + t];
            p0 += bf2f(r.x); p1 += bf2f(r.y); p2 += bf2f(r.z); p3 += bf2f(r.w);
        }
        #pragma unroll
        for (int o = 32; o > 0; o >>= 1) {
            p0 += __shfl_xor(p0, o, 64); p1 += __shfl_xor(p1, o, 64);
            p2 += __shfl_xor(p2, o, 64); p3 += __shfl_xor(p3, o, 64);
        }
        float acc = (float)deg * sb1[lane]
                  + p0 * sWp[lane] + p1 * sWp[64 + lane]
                  + p2 * sWp[128 + lane] + p3 * sWp[192 + lane];
        #pragma unroll
        for (int kk = 0; kk < 32; kk++) acc += __shfl(hs, kk, 64) * sW1[kk * 64 + lane];
        float d = (float)(deg > 0 ? deg : 1);
        float v = acc / d;
        e_feat[(size_t)e * 64 + lane] = f2bf(v);
        float r = v * att2;
        #pragma unroll
        for (int o = 32; o > 0; o >>= 1) r += __shfl_down(r, o, 64);
        if (lane == 0) e_att[e] = r;
    }
}

// ---------- fused softmax+PNA + node-blocked GEMM + lrelu + pools ----------
// scat bf16: per node 8 k-blocks of 32 ushorts padded to 40 (80 B, 16B-aligned);
// phase-B kg-strided reads land on 8 distinct bank groups (conflict-free).
// Phase B register-blocks 8 nodes per W-fragment load: W traffic 8x lower than
// per-node reload; peak live VGPRs ~60 -> no spill at launch_bounds(256,5).
__global__ __launch_bounds__(256, 5) void k_fused(
    const int* __restrict__ row_ptr, const int* __restrict__ csr,
    const float* __restrict__ xn_att, const float* __restrict__ e_att,
    const unsigned short* __restrict__ e_feat,
    const float* __restrict__ Wpost, const float* __restrict__ bpost,
    const int* __restrict__ mcount,
    float* __restrict__ sum_all, float* __restrict__ sum_mac)
{
    __shared__ __align__(16) unsigned short scat[32 * 320];   // 20,480 B
    const int lane = threadIdx.x & 63;
    const int wave = threadIdx.x >> 6;
    const int kg = lane >> 3;
    const int cg = lane & 7;
    const float2* W2 = (const float2*)Wpost;
    float2 bias = ((const float2*)bpost)[wave * 8 + cg];
    float2 pool = make_float2(0.f, 0.f), pmac = make_float2(0.f, 0.f);
    const int abase = (lane >> 5) * 40 + (lane & 31);
    const int nbatches = N_NODES / 32;  // 6250
    for (int b = blockIdx.x; b < nbatches; b += gridDim.x) {
        const int base = b * 32;
        __syncthreads();
        // ---- phase A: 8 nodes per wave, single pass, unnormalized softmax-PNA ----
        for (int i = 0; i < 8; i++) {
            int j = wave * 8 + i;
            int n = base + j;
            int start = row_ptr[n];
            int deg = row_ptr[n + 1] - start;
            float xn = xn_att[n];
            float sw = 0.f, s = 0.f, sq = 0.f, mx = -INFINITY, mn = INFINITY;
            int t = 0;
            for (; t + 4 <= deg; t += 4) {
                int e0 = csr[start + t],     e1 = csr[start + t + 1];
                int e2 = csr[start + t + 2], e3 = csr[start + t + 3];
                float w0 = __expf(lrelu(xn + e_att[e0]));
                float w1 = __expf(lrelu(xn + e_att[e1]));
                float w2 = __expf(lrelu(xn + e_att[e2]));
                float w3 = __expf(lrelu(xn + e_att[e3]));
                float v0 = bf2f(e_feat[(size_t)e0 * 64 + lane]) * w0;
                float v1 = bf2f(e_feat[(size_t)e1 * 64 + lane]) * w1;
                float v2 = bf2f(e_feat[(size_t)e2 * 64 + lane]) * w2;
                float v3 = bf2f(e_feat[(size_t)e3 * 64 + lane]) * w3;
                sw += w0 + w1 + w2 + w3;
                s  += v0 + v1 + v2 + v3;
                sq += v0 * v0 + v1 * v1 + v2 * v2 + v3 * v3;
                mx = fmaxf(fmaxf(mx, v0), fmaxf(fmaxf(v1, v2), v3));
                mn = fminf(fminf(mn, v0), fminf(fminf(v1, v2), v3));
            }
            for (; t < deg; t++) {
                int e = csr[start + t];
                float w = __expf(lrelu(xn + e_att[e]));
                float v = bf2f(e_feat[(size_t)e * 64 + lane]) * w;
                sw += w; s += v; sq += v * v;
                mx = fmaxf(mx, v); mn = fminf(mn, v);
            }
            float invD = 1.f / (sw + 1e-16f);
            float dc = (float)(deg > 0 ? deg : 1);
            float mean = s * invD / dc;
            float sqm  = sq * invD * invD / dc;
            float stdv = sqrtf(fmaxf(sqm - mean * mean, 0.f) + 1e-12f);
            unsigned short* row = &scat[j * 320];
            row[abase]        = f2bf(mean);
            row[80 + abase]   = f2bf(deg > 0 ? mx * invD : 0.f);
            row[160 + abase]  = f2bf(deg > 0 ? mn * invD : 0.f);
            row[240 + abase]  = f2bf(stdv);
        }
        __syncthreads();
        // ---- phase B: 8-node register blocks; W fragment reused across 8 nodes ----
        for (int jb = 0; jb < 32; jb += 8) {
            float2 acc[8];
            #pragma unroll
            for (int u = 0; u < 8; u++) acc[u] = make_float2(0.f, 0.f);
            #pragma unroll
            for (int i = 0; i < 4; i++) {
                float2 w[8];
                #pragma unroll
                for (int t = 0; t < 8; t++)
                    w[t] = W2[(size_t)(32 * kg + 8 * i + t) * 32 + wave * 8 + cg];
                #pragma unroll
                for (int u = 0; u < 8; u++) {
                    uint4 q = *(const uint4*)&scat[(jb + u) * 320 + kg * 40 + i * 8];
                    float c0 = __uint_as_float(q.x << 16), c1 = __uint_as_float(q.x & 0xffff0000u);
                    float c2 = __uint_as_float(q.y << 16), c3 = __uint_as_float(q.y & 0xffff0000u);
                    float c4 = __uint_as_float(q.z << 16), c5 = __uint_as_float(q.z & 0xffff0000u);
                    float c6 = __uint_as_float(q.w << 16), c7 = __uint_as_float(q.w & 0xffff0000u);
                    acc[u].x += c0 * w[0].x + c1 * w[1].x + c2 * w[2].x + c3 * w[3].x
                              + c4 * w[4].x + c5 * w[5].x + c6 * w[6].x + c7 * w[7].x;
                    acc[u].y += c0 * w[0].y + c1 * w[1].y + c2 * w[2].y + c3 * w[3].y
                              + c4 * w[4].y + c5 * w[5].y + c6 * w[6].y + c7 * w[7].y;
                }
            }
            #pragma unroll
            for (int u = 0; u < 8; u++) {
                float ax = acc[u].x, ay = acc[u].y;
                ax += __shfl_xor(ax, 8);  ay += __shfl_xor(ay, 8);
                ax += __shfl_xor(ax, 16); ay += __shfl_xor(ay, 16);
                ax += __shfl_xor(ax, 32); ay += __shfl_xor(ay, 32);
                if (kg == 0) {
                    float h0 = lrelu(ax + bias.x);
                    float h1 = lrelu(ay + bias.y);
                    float mc = (float)mcount[base + jb + u];
                    pool.x += h0; pool.y += h1;
                    pmac.x += mc * h0; pmac.y += mc * h1;
                }
            }
        }
    }
    if (kg == 0) {
        int c0 = wave * 16 + 2 * cg;
        atomicAdd(&sum_all[c0],     pool.x);
        atomicAdd(&sum_all[c0 + 1], pool.y);
        atomicAdd(&sum_mac[c0],     pmac.x);
        atomicAdd(&sum_mac[c0 + 1], pmac.y);
    }
}

// ---------- tiny MLP head ----------
__global__ __launch_bounds__(256) void k_final(
    const float* __restrict__ sum_all, const float* __restrict__ sum_mac,
    const float* __restrict__ Wm1, const float* __restrict__ bm1,
    const float* __restrict__ Wm2, const float* __restrict__ bm2,
    const float* __restrict__ Wm3, const float* __restrict__ bm3,
    float* __restrict__ out)
{
    __shared__ float spool[128];
    __shared__ float z1[64];
    __shared__ float z2[32];
    if (threadIdx.x < 64) {
        spool[threadIdx.x]      = sum_mac[threadIdx.x] / (float)N_MACRO;
        spool[64 + threadIdx.x] = sum_all[threadIdx.x] / (float)N_NODES;
    }
    __syncthreads();
    if (threadIdx.x < 64) {
        int j = threadIdx.x;
        float a = bm1[j];
        #pragma unroll 4
        for (int k = 0; k < 128; k++) a += spool[k] * Wm1[k * 64 + j];
        z1[j] = lrelu(a);
    }
    __syncthreads();
    if (threadIdx.x < 32) {
        int j = threadIdx.x;
        float a = bm2[j];
        #pragma unroll 4
        for (int k = 0; k < 64; k++) a += z1[k] * Wm2[k * 32 + j];
        z2[j] = lrelu(a);
    }
    __syncthreads();
    if (threadIdx.x == 0) {
        float a = bm3[0];
        #pragma unroll
        for (int k = 0; k < 32; k++) a += z2[k] * Wm3[k];
        out[0] = a;
    }
}

// ---------- launch ----------
extern "C" void kernel_launch(void* const* d_in, const int* in_sizes, int n_in,
                              void* d_out, int out_size, void* d_ws, size_t ws_size,
                              hipStream_t stream)
{
    const float* x        = (const float*)d_in[0];
    const float* fake_pos = (const float*)d_in[1];
    const int*   edge     = (const int*)d_in[2];
    const float* pinf     = (const float*)d_in[3];
    const int*   macro    = (const int*)d_in[4];
    const float* W1    = (const float*)d_in[5];
    const float* b1    = (const float*)d_in[6];
    const float* Wpin  = (const float*)d_in[7];
    const float* att   = (const float*)d_in[8];
    const float* Wpost = (const float*)d_in[9];
    const float* bpost = (const float*)d_in[10];
    const float* Wm1   = (const float*)d_in[11];
    const float* bm1   = (const float*)d_in[12];
    const float* Wm2   = (const float*)d_in[13];
    const float* bm2   = (const float*)d_in[14];
    const float* Wm3   = (const float*)d_in[15];
    const float* bm3   = (const float*)d_in[16];
    float* out = (float*)d_out;

    float* ws = (float*)d_ws;
    // layout (4-byte units); zero region = [0, 700128)
    float*    ismacro = ws;                         //   200,000
    float*    sum_all = ws + 200000;                //        64
    float*    sum_mac = ws + 200064;                //        64
    int*      mcount  = (int*)(ws + 200128);        //   200,000
    int*      cnt     = (int*)(ws + 400128);        //   300,000
    // end zero region (700,128)
    int*      row_ptr  = (int*)(ws + 700128);       //   300,001
    int*      partials = (int*)(ws + 1000132);      //       300
    float*    va       = ws + 1000432;              //        40
    int*      rank_n   = (int*)(ws + 1000472);      // 1,000,000
    int*      rank_e   = (int*)(ws + 2000472);      // 1,000,000
    int*      csr      = (int*)(ws + 3000472);      // 2,000,000
    ushort4*  pfh      = (ushort4*)(ws + 5000472);  // 1M x 8B = 2,000,000 units (16B-aligned)
    float*    e_att    = ws + 7000472;              //   100,000
    float*    xn_att   = ws + 7100472;              //   200,000
    unsigned short* h      = (unsigned short*)(ws + 7300472);  // 6.4M ushort (3.2M units)
    unsigned short* e_feat = (unsigned short*)(ws + 10500472); // 6.4M ushort (3.2M units)
    // total: 13,700,472 units ~= 54.8 MB

    const int* nidx = edge;
    const int* hidx = edge + NNZ;

    fill_f32<<<1024, 256, 0, stream>>>(ws, 700128LL, 0.f);
    k_ismacro<<<2, 256, 0, stream>>>(macro, ismacro, mcount);
    k_count<<<2048, 256, 0, stream>>>(nidx, hidx, cnt, rank_n, rank_e);
    k_va<<<1, 64, 0, stream>>>(W1, b1, att, va);
    k_h<<<2048, 256, 0, stream>>>(x, fake_pos, ismacro, va, h, xn_att);
    k_scan1<<<NB_SCAN, 256, 0, stream>>>(cnt, row_ptr, partials);
    k_scan2<<<1, 512, 0, stream>>>(partials);
    k_scan3<<<NB_SCAN, 256, 0, stream>>>(row_ptr, partials);
    k_scatter<<<2048, 256, 0, stream>>>(nidx, hidx, row_ptr, rank_n, rank_e,
                                        (const float4*)pinf, csr, pfh);
    k_he_agg<<<2048, 256, 0, stream>>>(row_ptr, csr, pfh, W1, Wpin, b1, att, h, e_feat, e_att);
    k_fused<<<1536, 256, 0, stream>>>(row_ptr, csr, xn_att, e_att, e_feat, Wpost, bpost,
                                      mcount, sum_all, sum_mac);
    k_final<<<1, 256, 0, stream>>>(sum_all, sum_mac, Wm1, bm1, Wm2, bm2, Wm3, bm3, out);
}

// Round 9
// 640.861 us; speedup vs baseline: 4.0104x; 4.0104x over previous
//
#include <hip/hip_runtime.h>
#include <math.h>

#define N_NODES 200000
#define N_HE    100000
#define NNZ     1000000
#define F_RAW   29
#define N_MACRO 512
#define SLOPE   0.1f
#define L_TOTAL (N_NODES + N_HE)   // 300000 combined counters
#define NB_SCAN 293                // ceil(300000/1024)

__device__ __forceinline__ float lrelu(float v) { return v >= 0.f ? v : SLOPE * v; }
__device__ __forceinline__ float bf2f(unsigned short u) { return __uint_as_float(((unsigned)u) << 16); }
__device__ __forceinline__ unsigned short f2bf(float f) {
    unsigned u = __float_as_uint(f);
    unsigned r = u + 0x7FFFu + ((u >> 16) & 1u);   // RNE
    return (unsigned short)(r >> 16);
}

// ---------- fills ----------
__global__ __launch_bounds__(256) void fill_f32(float* p, long long n, float v) {
    long long i = (long long)blockIdx.x * blockDim.x + threadIdx.x;
    long long st = (long long)gridDim.x * blockDim.x;
    for (; i < n; i += st) p[i] = v;
}

__global__ __launch_bounds__(256) void k_ismacro(const int* __restrict__ mi,
                                                 float* __restrict__ ismacro, int* __restrict__ mcount) {
    int i = blockIdx.x * blockDim.x + threadIdx.x;
    if (i < N_MACRO) {
        ismacro[mi[i]] = 1.0f;
        atomicAdd(&mcount[mi[i]], 1);
    }
}

// ---------- va[k] = W1[k,:]·att[:64], va[32] = b1·att[:64] ----------
__global__ __launch_bounds__(64) void k_va(const float* __restrict__ W1, const float* __restrict__ b1,
                                           const float* __restrict__ att, float* __restrict__ va) {
    int t = threadIdx.x;
    if (t < 32) {
        float a = 0.f;
        for (int c = 0; c < 64; c++) a += W1[t * 64 + c] * att[c];
        va[t] = a;
    } else if (t == 32) {
        float a = 0.f;
        for (int c = 0; c < 64; c++) a += b1[c] * att[c];
        va[32] = a;
    }
}

// ---------- build h rows (32 bf16) + xn_att ----------
__global__ __launch_bounds__(256) void k_h(
    const float* __restrict__ x, const float* __restrict__ fp,
    const float* __restrict__ ismacro, const float* __restrict__ va,
    unsigned short* __restrict__ h, float* __restrict__ xn_att)
{
    const int lane = threadIdx.x & 63;
    const int half = lane >> 5, k = lane & 31;
    int wid = (blockIdx.x * blockDim.x + threadIdx.x) >> 6;
    int nw = (gridDim.x * blockDim.x) >> 6;
    float vak = va[k];
    float c0 = va[32];
    for (int base = wid * 2; base < N_NODES; base += nw * 2) {
        int n = base + half;
        float v;
        if (k < 29)       v = x[(size_t)n * F_RAW + k];
        else if (k == 29) v = fp[2 * n];
        else if (k == 30) v = fp[2 * n + 1];
        else              v = ismacro[n];
        h[(size_t)n * 32 + k] = f2bf(v);
        float r = v * vak;
        #pragma unroll
        for (int o = 16; o > 0; o >>= 1) r += __shfl_xor(r, o, 32);
        if (k == 0) xn_att[n] = r + c0;
    }
}

// ---------- counts + per-pin ranks (atomicAdd old value) ----------
__global__ __launch_bounds__(256) void k_count(
    const int* __restrict__ nidx, const int* __restrict__ hidx,
    int* __restrict__ cnt, int* __restrict__ rank_n, int* __restrict__ rank_e)
{
    int i = blockIdx.x * blockDim.x + threadIdx.x;
    int st = gridDim.x * blockDim.x;
    for (int p = i; p < NNZ; p += st) {
        rank_n[p] = atomicAdd(&cnt[nidx[p]], 1);
        rank_e[p] = atomicAdd(&cnt[N_NODES + hidx[p]], 1);
    }
}

// ---------- scan of cnt (length L_TOTAL) -> row_ptr ----------
__global__ __launch_bounds__(256) void k_scan1(const int* __restrict__ cnt,
                                               int* __restrict__ row_ptr, int* __restrict__ partials)
{
    __shared__ int sA[256], sB[256];
    const int t = threadIdx.x;
    const int base = blockIdx.x * 1024 + t * 4;
    int v0 = base + 0 < L_TOTAL ? cnt[base + 0] : 0;
    int v1 = base + 1 < L_TOTAL ? cnt[base + 1] : 0;
    int v2 = base + 2 < L_TOTAL ? cnt[base + 2] : 0;
    int v3 = base + 3 < L_TOTAL ? cnt[base + 3] : 0;
    sA[t] = v0 + v1 + v2 + v3;
    __syncthreads();
    int* src = sA; int* dst = sB;
    for (int off = 1; off < 256; off <<= 1) {
        int v = src[t];
        if (t >= off) v += src[t - off];
        dst[t] = v;
        __syncthreads();
        int* tmp = src; src = dst; dst = tmp;
    }
    int excl = t > 0 ? src[t - 1] : 0;
    if (base + 0 < L_TOTAL) row_ptr[base + 0] = excl;
    if (base + 1 < L_TOTAL) row_ptr[base + 1] = excl + v0;
    if (base + 2 < L_TOTAL) row_ptr[base + 2] = excl + v0 + v1;
    if (base + 3 < L_TOTAL) row_ptr[base + 3] = excl + v0 + v1 + v2;
    if (t == 255) partials[blockIdx.x] = src[255];
}

__global__ __launch_bounds__(512) void k_scan2(int* __restrict__ partials)
{
    __shared__ int sA[512], sB[512];
    const int t = threadIdx.x;
    sA[t] = t < NB_SCAN ? partials[t] : 0;
    __syncthreads();
    int* src = sA; int* dst = sB;
    for (int off = 1; off < 512; off <<= 1) {
        int v = src[t];
        if (t >= off) v += src[t - off];
        dst[t] = v;
        __syncthreads();
        int* tmp = src; src = dst; dst = tmp;
    }
    if (t < NB_SCAN) partials[t] = t > 0 ? src[t - 1] : 0;
    if (t == 0) partials[NB_SCAN] = src[511];
}

__global__ __launch_bounds__(256) void k_scan3(int* __restrict__ row_ptr, const int* __restrict__ partials)
{
    const int base = blockIdx.x * 1024 + threadIdx.x * 4;
    int add = partials[blockIdx.x];
    #pragma unroll
    for (int k = 0; k < 4; k++)
        if (base + k < L_TOTAL) row_ptr[base + k] += add;
    if (blockIdx.x == 0 && threadIdx.x == 0) row_ptr[L_TOTAL] = partials[NB_SCAN];
}

// ---------- atomic-free scatter: csr + bf16 pinf into he-slot order ----------
__global__ __launch_bounds__(256) void k_scatter(
    const int* __restrict__ nidx, const int* __restrict__ hidx,
    const int* __restrict__ row_ptr,
    const int* __restrict__ rank_n, const int* __restrict__ rank_e,
    const float4* __restrict__ pf4, int* __restrict__ csr, ushort4* __restrict__ pfh)
{
    int i = blockIdx.x * blockDim.x + threadIdx.x;
    int st = gridDim.x * blockDim.x;
    for (int p = i; p < NNZ; p += st) {
        int n = nidx[p], e = hidx[p];
        csr[row_ptr[n] + rank_n[p]] = e;
        int pe = row_ptr[N_NODES + e] + rank_e[p];  // absolute slot (>= NNZ)
        csr[pe] = n;
        float4 q = pf4[p];
        ushort4 r;
        r.x = f2bf(q.x); r.y = f2bf(q.y); r.z = f2bf(q.z); r.w = f2bf(q.w);
        pfh[pe - NNZ] = r;
    }
}

// ---------- he-side: gather bf16 h rows + coalesced bf16 pinf, matvec W1 ----------
__global__ __launch_bounds__(256) void k_he_agg(
    const int* __restrict__ row_ptr, const int* __restrict__ csr,
    const ushort4* __restrict__ pfh,
    const float* __restrict__ W1, const float* __restrict__ Wpin,
    const float* __restrict__ b1, const float* __restrict__ att,
    const unsigned short* __restrict__ h,
    unsigned short* __restrict__ e_feat, float* __restrict__ e_att)
{
    __shared__ float sW1[32 * 64];
    __shared__ float sWp[4 * 64];
    __shared__ float sb1[64];
    for (int i = threadIdx.x; i < 32 * 64; i += 256) sW1[i] = W1[i];
    for (int i = threadIdx.x; i < 4 * 64; i += 256) sWp[i] = Wpin[i];
    if (threadIdx.x < 64) sb1[threadIdx.x] = b1[threadIdx.x];
    __syncthreads();
    const int lane = threadIdx.x & 63;
    const int half = lane >> 5, k32 = lane & 31;
    float att2 = att[64 + lane];
    int wid = (blockIdx.x * blockDim.x + threadIdx.x) >> 6;
    int nw = (gridDim.x * blockDim.x) >> 6;
    for (int e = wid; e < N_HE; e += nw) {
        int start = row_ptr[N_NODES + e];
        int deg = row_ptr[N_NODES + e + 1] - start;
        // gather h rows: each half-wave loads one 64B bf16 row per step
        float hs = 0.f;
        for (int t0 = 0; t0 < deg; t0 += 8) {
            #pragma unroll
            for (int r = 0; r < 4; r++) {
                int t = t0 + 2 * r + half;
                if (t < deg) {
                    int n = csr[start + t];
                    hs += bf2f(h[(size_t)n * 32 + k32]);
                }
            }
        }
        hs += __shfl_xor(hs, 32, 64);
        // coalesced bf16 pinf sums
        float p0 = 0.f, p1 = 0.f, p2 = 0.f, p3 = 0.f;
        for (int t = lane; t < deg; t += 64) {
            ushort4 r = pfh[start - NNZ + t];
            p0 += bf2f(r.x); p1 += bf2f(r.y); p2 += bf2f(r.z); p3 += bf2f(r.w);
        }
        #pragma unroll
        for (int o = 32; o > 0; o >>= 1) {
            p0 += __shfl_xor(p0, o, 64); p1 += __shfl_xor(p1, o, 64);
            p2 += __shfl_xor(p2, o, 64); p3 += __shfl_xor(p3, o, 64);
        }
        float acc = (float)deg * sb1[lane]
                  + p0 * sWp[lane] + p1 * sWp[64 + lane]
                  + p2 * sWp[128 + lane] + p3 * sWp[192 + lane];
        #pragma unroll
        for (int kk = 0; kk < 32; kk++) acc += __shfl(hs, kk, 64) * sW1[kk * 64 + lane];
        float d = (float)(deg > 0 ? deg : 1);
        float v = acc / d;
        e_feat[(size_t)e * 64 + lane] = f2bf(v);
        float r = v * att2;
        #pragma unroll
        for (int o = 32; o > 0; o >>= 1) r += __shfl_down(r, o, 64);
        if (lane == 0) e_att[e] = r;
    }
}

// ---------- fused softmax+PNA + GEMM + lrelu + pools (R6 structure, 16-node batch) ----------
// scat fp32: per node 8 blocks of 32 floats padded to 36 (stride-36 kg blocks ->
// phase-B kg reads hit distinct bank groups). 16-node batch: LDS 18.4 KB -> 8 blocks/CU.
__global__ __launch_bounds__(256, 4) void k_fused(
    const int* __restrict__ row_ptr, const int* __restrict__ csr,
    const float* __restrict__ xn_att, const float* __restrict__ e_att,
    const unsigned short* __restrict__ e_feat,
    const float* __restrict__ Wpost, const float* __restrict__ bpost,
    const int* __restrict__ mcount,
    float* __restrict__ sum_all, float* __restrict__ sum_mac)
{
    __shared__ __align__(16) float scat[16 * 288];   // 18,432 B
    const int lane = threadIdx.x & 63;
    const int wave = threadIdx.x >> 6;
    const int kg = lane >> 3;
    const int cg = lane & 7;
    float2 wreg[32];
    {
        const float2* W2 = (const float2*)Wpost;
        #pragma unroll
        for (int t = 0; t < 32; t++)
            wreg[t] = W2[(size_t)(32 * kg + t) * 32 + wave * 8 + cg];
    }
    float2 bias = ((const float2*)bpost)[wave * 8 + cg];
    float2 pool = make_float2(0.f, 0.f), pmac = make_float2(0.f, 0.f);
    const int off_c = 36 * (lane >> 5) + (lane & 31);
    const int nbatches = N_NODES / 16;  // 12500
    for (int b = blockIdx.x; b < nbatches; b += gridDim.x) {
        const int base = b * 16;
        __syncthreads();
        // ---- phase A: 4 nodes per wave, single pass, unnormalized softmax-PNA ----
        for (int i = 0; i < 4; i++) {
            int j = wave * 4 + i;
            int n = base + j;
            int start = row_ptr[n];
            int deg = row_ptr[n + 1] - start;
            float xn = xn_att[n];
            float sw = 0.f, s = 0.f, sq = 0.f, mx = -INFINITY, mn = INFINITY;
            int t = 0;
            for (; t + 4 <= deg; t += 4) {
                int e0 = csr[start + t],     e1 = csr[start + t + 1];
                int e2 = csr[start + t + 2], e3 = csr[start + t + 3];
                float w0 = __expf(lrelu(xn + e_att[e0]));
                float w1 = __expf(lrelu(xn + e_att[e1]));
                float w2 = __expf(lrelu(xn + e_att[e2]));
                float w3 = __expf(lrelu(xn + e_att[e3]));
                float v0 = bf2f(e_feat[(size_t)e0 * 64 + lane]) * w0;
                float v1 = bf2f(e_feat[(size_t)e1 * 64 + lane]) * w1;
                float v2 = bf2f(e_feat[(size_t)e2 * 64 + lane]) * w2;
                float v3 = bf2f(e_feat[(size_t)e3 * 64 + lane]) * w3;
                sw += w0 + w1 + w2 + w3;
                s  += v0 + v1 + v2 + v3;
                sq += v0 * v0 + v1 * v1 + v2 * v2 + v3 * v3;
                mx = fmaxf(fmaxf(mx, v0), fmaxf(fmaxf(v1, v2), v3));
                mn = fminf(fminf(mn, v0), fminf(fminf(v1, v2), v3));
            }
            for (; t < deg; t++) {
                int e = csr[start + t];
                float w = __expf(lrelu(xn + e_att[e]));
                float v = bf2f(e_feat[(size_t)e * 64 + lane]) * w;
                sw += w; s += v; sq += v * v;
                mx = fmaxf(mx, v); mn = fminf(mn, v);
            }
            float invD = 1.f / (sw + 1e-16f);
            float dc = (float)(deg > 0 ? deg : 1);
            float mean = s * invD / dc;
            float sqm  = sq * invD * invD / dc;
            float stdv = sqrtf(fmaxf(sqm - mean * mean, 0.f) + 1e-12f);
            float* row = &scat[j * 288];
            row[off_c]       = mean;
            row[72 + off_c]  = deg > 0 ? mx * invD : 0.f;
            row[144 + off_c] = deg > 0 ? mn * invD : 0.f;
            row[216 + off_c] = stdv;
        }
        __syncthreads();
        // ---- phase B: all 16 nodes, kg/cg decomposition, shfl reduce ----
        for (int j = 0; j < 16; j++) {
            const float4* sc = (const float4*)&scat[j * 288 + kg * 36];
            float2 a = make_float2(0.f, 0.f);
            #pragma unroll
            for (int i = 0; i < 8; i++) {
                float4 c4 = sc[i];
                a.x += c4.x * wreg[4 * i + 0].x + c4.y * wreg[4 * i + 1].x
                     + c4.z * wreg[4 * i + 2].x + c4.w * wreg[4 * i + 3].x;
                a.y += c4.x * wreg[4 * i + 0].y + c4.y * wreg[4 * i + 1].y
                     + c4.z * wreg[4 * i + 2].y + c4.w * wreg[4 * i + 3].y;
            }
            a.x += __shfl_xor(a.x, 8);  a.y += __shfl_xor(a.y, 8);
            a.x += __shfl_xor(a.x, 16); a.y += __shfl_xor(a.y, 16);
            a.x += __shfl_xor(a.x, 32); a.y += __shfl_xor(a.y, 32);
            if (kg == 0) {
                float h0 = lrelu(a.x + bias.x);
                float h1 = lrelu(a.y + bias.y);
                float mc = (float)mcount[base + j];
                pool.x += h0; pool.y += h1;
                pmac.x += mc * h0; pmac.y += mc * h1;
            }
        }
    }
    if (kg == 0) {
        int c0 = wave * 16 + 2 * cg;
        atomicAdd(&sum_all[c0],     pool.x);
        atomicAdd(&sum_all[c0 + 1], pool.y);
        atomicAdd(&sum_mac[c0],     pmac.x);
        atomicAdd(&sum_mac[c0 + 1], pmac.y);
    }
}

// ---------- tiny MLP head ----------
__global__ __launch_bounds__(256) void k_final(
    const float* __restrict__ sum_all, const float* __restrict__ sum_mac,
    const float* __restrict__ Wm1, const float* __restrict__ bm1,
    const float* __restrict__ Wm2, const float* __restrict__ bm2,
    const float* __restrict__ Wm3, const float* __restrict__ bm3,
    float* __restrict__ out)
{
    __shared__ float spool[128];
    __shared__ float z1[64];
    __shared__ float z2[32];
    if (threadIdx.x < 64) {
        spool[threadIdx.x]      = sum_mac[threadIdx.x] / (float)N_MACRO;
        spool[64 + threadIdx.x] = sum_all[threadIdx.x] / (float)N_NODES;
    }
    __syncthreads();
    if (threadIdx.x < 64) {
        int j = threadIdx.x;
        float a = bm1[j];
        #pragma unroll 4
        for (int k = 0; k < 128; k++) a += spool[k] * Wm1[k * 64 + j];
        z1[j] = lrelu(a);
    }
    __syncthreads();
    if (threadIdx.x < 32) {
        int j = threadIdx.x;
        float a = bm2[j];
        #pragma unroll 4
        for (int k = 0; k < 64; k++) a += z1[k] * Wm2[k * 32 + j];
        z2[j] = lrelu(a);
    }
    __syncthreads();
    if (threadIdx.x == 0) {
        float a = bm3[0];
        #pragma unroll
        for (int k = 0; k < 32; k++) a += z2[k] * Wm3[k];
        out[0] = a;
    }
}

// ---------- launch ----------
extern "C" void kernel_launch(void* const* d_in, const int* in_sizes, int n_in,
                              void* d_out, int out_size, void* d_ws, size_t ws_size,
                              hipStream_t stream)
{
    const float* x        = (const float*)d_in[0];
    const float* fake_pos = (const float*)d_in[1];
    const int*   edge     = (const int*)d_in[2];
    const float* pinf     = (const float*)d_in[3];
    const int*   macro    = (const int*)d_in[4];
    const float* W1    = (const float*)d_in[5];
    const float* b1    = (const float*)d_in[6];
    const float* Wpin  = (const float*)d_in[7];
    const float* att   = (const float*)d_in[8];
    const float* Wpost = (const float*)d_in[9];
    const float* bpost = (const float*)d_in[10];
    const float* Wm1   = (const float*)d_in[11];
    const float* bm1   = (const float*)d_in[12];
    const float* Wm2   = (const float*)d_in[13];
    const float* bm2   = (const float*)d_in[14];
    const float* Wm3   = (const float*)d_in[15];
    const float* bm3   = (const float*)d_in[16];
    float* out = (float*)d_out;

    float* ws = (float*)d_ws;
    // layout (4-byte units); zero region = [0, 700128)
    float*    ismacro = ws;                         //   200,000
    float*    sum_all = ws + 200000;                //        64
    float*    sum_mac = ws + 200064;                //        64
    int*      mcount  = (int*)(ws + 200128);        //   200,000
    int*      cnt     = (int*)(ws + 400128);        //   300,000
    // end zero region (700,128)
    int*      row_ptr  = (int*)(ws + 700128);       //   300,001
    int*      partials = (int*)(ws + 1000132);      //       300
    float*    va       = ws + 1000432;              //        40
    int*      rank_n   = (int*)(ws + 1000472);      // 1,000,000
    int*      rank_e   = (int*)(ws + 2000472);      // 1,000,000
    int*      csr      = (int*)(ws + 3000472);      // 2,000,000
    ushort4*  pfh      = (ushort4*)(ws + 5000472);  // 1M x 8B = 2,000,000 units (16B-aligned)
    float*    e_att    = ws + 7000472;              //   100,000
    float*    xn_att   = ws + 7100472;              //   200,000
    unsigned short* h      = (unsigned short*)(ws + 7300472);  // 6.4M ushort (3.2M units)
    unsigned short* e_feat = (unsigned short*)(ws + 10500472); // 6.4M ushort (3.2M units)
    // total: 13,700,472 units ~= 54.8 MB

    const int* nidx = edge;
    const int* hidx = edge + NNZ;

    fill_f32<<<1024, 256, 0, stream>>>(ws, 700128LL, 0.f);
    k_ismacro<<<2, 256, 0, stream>>>(macro, ismacro, mcount);
    k_count<<<2048, 256, 0, stream>>>(nidx, hidx, cnt, rank_n, rank_e);
    k_va<<<1, 64, 0, stream>>>(W1, b1, att, va);
    k_h<<<2048, 256, 0, stream>>>(x, fake_pos, ismacro, va, h, xn_att);
    k_scan1<<<NB_SCAN, 256, 0, stream>>>(cnt, row_ptr, partials);
    k_scan2<<<1, 512, 0, stream>>>(partials);
    k_scan3<<<NB_SCAN, 256, 0, stream>>>(row_ptr, partials);
    k_scatter<<<2048, 256, 0, stream>>>(nidx, hidx, row_ptr, rank_n, rank_e,
                                        (const float4*)pinf, csr, pfh);
    k_he_agg<<<2048, 256, 0, stream>>>(row_ptr, csr, pfh, W1, Wpin, b1, att, h, e_feat, e_att);
    k_fused<<<2048, 256, 0, stream>>>(row_ptr, csr, xn_att, e_att, e_feat, Wpost, bpost,
                                      mcount, sum_all, sum_mac);
    k_final<<<1, 256, 0, stream>>>(sum_all, sum_mac, Wm1, bm1, Wm2, bm2, Wm3, bm3, out);
}

// Round 10
// 552.914 us; speedup vs baseline: 4.6483x; 1.1591x over previous
//
#include <hip/hip_runtime.h>
#include <math.h>

#define N_NODES 200000
#define N_HE    100000
#define NNZ     1000000
#define F_RAW   29
#define N_MACRO 512
#define SLOPE   0.1f
#define L_TOTAL (N_NODES + N_HE)   // 300000 combined counters
#define NB_SCAN 293                // ceil(300000/1024)

typedef __attribute__((ext_vector_type(8))) short bf16x8;
typedef __attribute__((ext_vector_type(4))) float f32x4;

__device__ __forceinline__ float lrelu(float v) { return v >= 0.f ? v : SLOPE * v; }
__device__ __forceinline__ float bf2f(unsigned short u) { return __uint_as_float(((unsigned)u) << 16); }
__device__ __forceinline__ unsigned short f2bf(float f) {
    unsigned u = __float_as_uint(f);
    unsigned r = u + 0x7FFFu + ((u >> 16) & 1u);   // RNE
    return (unsigned short)(r >> 16);
}

// ---------- fills ----------
__global__ __launch_bounds__(256) void fill_f32(float* p, long long n, float v) {
    long long i = (long long)blockIdx.x * blockDim.x + threadIdx.x;
    long long st = (long long)gridDim.x * blockDim.x;
    for (; i < n; i += st) p[i] = v;
}

__global__ __launch_bounds__(256) void k_ismacro(const int* __restrict__ mi,
                                                 float* __restrict__ ismacro, int* __restrict__ mcount) {
    int i = blockIdx.x * blockDim.x + threadIdx.x;
    if (i < N_MACRO) {
        ismacro[mi[i]] = 1.0f;
        atomicAdd(&mcount[mi[i]], 1);
    }
}

// ---------- va[k] = W1[k,:]·att[:64], va[32] = b1·att[:64] ----------
__global__ __launch_bounds__(64) void k_va(const float* __restrict__ W1, const float* __restrict__ b1,
                                           const float* __restrict__ att, float* __restrict__ va) {
    int t = threadIdx.x;
    if (t < 32) {
        float a = 0.f;
        for (int c = 0; c < 64; c++) a += W1[t * 64 + c] * att[c];
        va[t] = a;
    } else if (t == 32) {
        float a = 0.f;
        for (int c = 0; c < 64; c++) a += b1[c] * att[c];
        va[32] = a;
    }
}

// ---------- build h rows (32 bf16) + xn_att ----------
__global__ __launch_bounds__(256) void k_h(
    const float* __restrict__ x, const float* __restrict__ fp,
    const float* __restrict__ ismacro, const float* __restrict__ va,
    unsigned short* __restrict__ h, float* __restrict__ xn_att)
{
    const int lane = threadIdx.x & 63;
    const int half = lane >> 5, k = lane & 31;
    int wid = (blockIdx.x * blockDim.x + threadIdx.x) >> 6;
    int nw = (gridDim.x * blockDim.x) >> 6;
    float vak = va[k];
    float c0 = va[32];
    for (int base = wid * 2; base < N_NODES; base += nw * 2) {
        int n = base + half;
        float v;
        if (k < 29)       v = x[(size_t)n * F_RAW + k];
        else if (k == 29) v = fp[2 * n];
        else if (k == 30) v = fp[2 * n + 1];
        else              v = ismacro[n];
        h[(size_t)n * 32 + k] = f2bf(v);
        float r = v * vak;
        #pragma unroll
        for (int o = 16; o > 0; o >>= 1) r += __shfl_xor(r, o, 32);
        if (k == 0) xn_att[n] = r + c0;
    }
}

// ---------- counts + per-pin ranks (atomicAdd old value) ----------
__global__ __launch_bounds__(256) void k_count(
    const int* __restrict__ nidx, const int* __restrict__ hidx,
    int* __restrict__ cnt, int* __restrict__ rank_n, int* __restrict__ rank_e)
{
    int i = blockIdx.x * blockDim.x + threadIdx.x;
    int st = gridDim.x * blockDim.x;
    for (int p = i; p < NNZ; p += st) {
        rank_n[p] = atomicAdd(&cnt[nidx[p]], 1);
        rank_e[p] = atomicAdd(&cnt[N_NODES + hidx[p]], 1);
    }
}

// ---------- scan of cnt (length L_TOTAL) -> row_ptr ----------
__global__ __launch_bounds__(256) void k_scan1(const int* __restrict__ cnt,
                                               int* __restrict__ row_ptr, int* __restrict__ partials)
{
    __shared__ int sA[256], sB[256];
    const int t = threadIdx.x;
    const int base = blockIdx.x * 1024 + t * 4;
    int v0 = base + 0 < L_TOTAL ? cnt[base + 0] : 0;
    int v1 = base + 1 < L_TOTAL ? cnt[base + 1] : 0;
    int v2 = base + 2 < L_TOTAL ? cnt[base + 2] : 0;
    int v3 = base + 3 < L_TOTAL ? cnt[base + 3] : 0;
    sA[t] = v0 + v1 + v2 + v3;
    __syncthreads();
    int* src = sA; int* dst = sB;
    for (int off = 1; off < 256; off <<= 1) {
        int v = src[t];
        if (t >= off) v += src[t - off];
        dst[t] = v;
        __syncthreads();
        int* tmp = src; src = dst; dst = tmp;
    }
    int excl = t > 0 ? src[t - 1] : 0;
    if (base + 0 < L_TOTAL) row_ptr[base + 0] = excl;
    if (base + 1 < L_TOTAL) row_ptr[base + 1] = excl + v0;
    if (base + 2 < L_TOTAL) row_ptr[base + 2] = excl + v0 + v1;
    if (base + 3 < L_TOTAL) row_ptr[base + 3] = excl + v0 + v1 + v2;
    if (t == 255) partials[blockIdx.x] = src[255];
}

__global__ __launch_bounds__(512) void k_scan2(int* __restrict__ partials)
{
    __shared__ int sA[512], sB[512];
    const int t = threadIdx.x;
    sA[t] = t < NB_SCAN ? partials[t] : 0;
    __syncthreads();
    int* src = sA; int* dst = sB;
    for (int off = 1; off < 512; off <<= 1) {
        int v = src[t];
        if (t >= off) v += src[t - off];
        dst[t] = v;
        __syncthreads();
        int* tmp = src; src = dst; dst = tmp;
    }
    if (t < NB_SCAN) partials[t] = t > 0 ? src[t - 1] : 0;
    if (t == 0) partials[NB_SCAN] = src[511];
}

__global__ __launch_bounds__(256) void k_scan3(int* __restrict__ row_ptr, const int* __restrict__ partials)
{
    const int base = blockIdx.x * 1024 + threadIdx.x * 4;
    int add = partials[blockIdx.x];
    #pragma unroll
    for (int k = 0; k < 4; k++)
        if (base + k < L_TOTAL) row_ptr[base + k] += add;
    if (blockIdx.x == 0 && threadIdx.x == 0) row_ptr[L_TOTAL] = partials[NB_SCAN];
}

// ---------- atomic-free scatter: csr + bf16 pinf into he-slot order ----------
__global__ __launch_bounds__(256) void k_scatter(
    const int* __restrict__ nidx, const int* __restrict__ hidx,
    const int* __restrict__ row_ptr,
    const int* __restrict__ rank_n, const int* __restrict__ rank_e,
    const float4* __restrict__ pf4, int* __restrict__ csr, ushort4* __restrict__ pfh)
{
    int i = blockIdx.x * blockDim.x + threadIdx.x;
    int st = gridDim.x * blockDim.x;
    for (int p = i; p < NNZ; p += st) {
        int n = nidx[p], e = hidx[p];
        csr[row_ptr[n] + rank_n[p]] = e;
        int pe = row_ptr[N_NODES + e] + rank_e[p];  // absolute slot (>= NNZ)
        csr[pe] = n;
        float4 q = pf4[p];
        ushort4 r;
        r.x = f2bf(q.x); r.y = f2bf(q.y); r.z = f2bf(q.z); r.w = f2bf(q.w);
        pfh[pe - NNZ] = r;
    }
}

// ---------- he-side: gather bf16 h rows + coalesced bf16 pinf, matvec W1 ----------
__global__ __launch_bounds__(256) void k_he_agg(
    const int* __restrict__ row_ptr, const int* __restrict__ csr,
    const ushort4* __restrict__ pfh,
    const float* __restrict__ W1, const float* __restrict__ Wpin,
    const float* __restrict__ b1, const float* __restrict__ att,
    const unsigned short* __restrict__ h,
    unsigned short* __restrict__ e_feat, float* __restrict__ e_att)
{
    __shared__ float sW1[32 * 64];
    __shared__ float sWp[4 * 64];
    __shared__ float sb1[64];
    for (int i = threadIdx.x; i < 32 * 64; i += 256) sW1[i] = W1[i];
    for (int i = threadIdx.x; i < 4 * 64; i += 256) sWp[i] = Wpin[i];
    if (threadIdx.x < 64) sb1[threadIdx.x] = b1[threadIdx.x];
    __syncthreads();
    const int lane = threadIdx.x & 63;
    const int half = lane >> 5, k32 = lane & 31;
    float att2 = att[64 + lane];
    int wid = (blockIdx.x * blockDim.x + threadIdx.x) >> 6;
    int nw = (gridDim.x * blockDim.x) >> 6;
    for (int e = wid; e < N_HE; e += nw) {
        int start = row_ptr[N_NODES + e];
        int deg = row_ptr[N_NODES + e + 1] - start;
        // gather h rows: each half-wave loads one 64B bf16 row per step
        float hs = 0.f;
        for (int t0 = 0; t0 < deg; t0 += 8) {
            #pragma unroll
            for (int r = 0; r < 4; r++) {
                int t = t0 + 2 * r + half;
                if (t < deg) {
                    int n = csr[start + t];
                    hs += bf2f(h[(size_t)n * 32 + k32]);
                }
            }
        }
        hs += __shfl_xor(hs, 32, 64);
        // coalesced bf16 pinf sums
        float p0 = 0.f, p1 = 0.f, p2 = 0.f, p3 = 0.f;
        for (int t = lane; t < deg; t += 64) {
            ushort4 r = pfh[start - NNZ + t];
            p0 += bf2f(r.x); p1 += bf2f(r.y); p2 += bf2f(r.z); p3 += bf2f(r.w);
        }
        #pragma unroll
        for (int o = 32; o > 0; o >>= 1) {
            p0 += __shfl_xor(p0, o, 64); p1 += __shfl_xor(p1, o, 64);
            p2 += __shfl_xor(p2, o, 64); p3 += __shfl_xor(p3, o, 64);
        }
        float acc = (float)deg * sb1[lane]
                  + p0 * sWp[lane] + p1 * sWp[64 + lane]
                  + p2 * sWp[128 + lane] + p3 * sWp[192 + lane];
        #pragma unroll
        for (int kk = 0; kk < 32; kk++) acc += __shfl(hs, kk, 64) * sW1[kk * 64 + lane];
        float d = (float)(deg > 0 ? deg : 1);
        float v = acc / d;
        e_feat[(size_t)e * 64 + lane] = f2bf(v);
        float r = v * att2;
        #pragma unroll
        for (int o = 32; o > 0; o >>= 1) r += __shfl_down(r, o, 64);
        if (lane == 0) e_att[e] = r;
    }
}

// ---------- fused softmax+PNA + MFMA post-GEMM + lrelu + pools ----------
// Phase A (unchanged from R9): 4 nodes/wave, single pass, unnormalized softmax-PNA;
// stats stored bf16 row-major into scat[16][264] (256 + 8 pad bf16; 528 B stride).
// Phase B: D(16 nodes x 16 ch/wave) = A(16x256) x B(256x16) via 8x
// mfma_f32_16x16x32_bf16. A-frag: lane reads 8 consecutive bf16 at
// scat[lane&15][quad*8 + 32*s] (one 16B LDS read per MFMA). B-frag: W bf16 in 32
// persistent VGPRs, loaded once. C-layout (verified): col=lane&15 (channel),
// row=quad*4+reg (node).
__global__ __launch_bounds__(256, 4) void k_fused(
    const int* __restrict__ row_ptr, const int* __restrict__ csr,
    const float* __restrict__ xn_att, const float* __restrict__ e_att,
    const unsigned short* __restrict__ e_feat,
    const float* __restrict__ Wpost, const float* __restrict__ bpost,
    const int* __restrict__ mcount,
    float* __restrict__ sum_all, float* __restrict__ sum_mac)
{
    __shared__ __align__(16) unsigned short scat[16 * 264];   // 8448 B
    const int lane = threadIdx.x & 63;
    const int wave = threadIdx.x >> 6;
    const int quad = lane >> 4;     // 0..3
    const int nn   = lane & 15;     // channel offset within wave's 16 (B/D col, A row=m uses same field)
    // B fragments: lane holds W[k = 32s + quad*8 + j][c = wave*16 + nn], j=0..7
    bf16x8 wfrag[8];
    #pragma unroll
    for (int s = 0; s < 8; s++) {
        bf16x8 w;
        #pragma unroll
        for (int j = 0; j < 8; j++)
            w[j] = (short)f2bf(Wpost[(size_t)(32 * s + quad * 8 + j) * 64 + wave * 16 + nn]);
        wfrag[s] = w;
    }
    float bias = bpost[wave * 16 + nn];
    float pool = 0.f, pmac = 0.f;
    const int nbatches = N_NODES / 16;  // 12500
    for (int b = blockIdx.x; b < nbatches; b += gridDim.x) {
        const int base = b * 16;
        __syncthreads();
        // ---- phase A: 4 nodes per wave, single pass, unnormalized softmax-PNA ----
        for (int i = 0; i < 4; i++) {
            int j = wave * 4 + i;
            int n = base + j;
            int start = row_ptr[n];
            int deg = row_ptr[n + 1] - start;
            float xn = xn_att[n];
            float sw = 0.f, s = 0.f, sq = 0.f, mx = -INFINITY, mn = INFINITY;
            int t = 0;
            for (; t + 4 <= deg; t += 4) {
                int e0 = csr[start + t],     e1 = csr[start + t + 1];
                int e2 = csr[start + t + 2], e3 = csr[start + t + 3];
                float w0 = __expf(lrelu(xn + e_att[e0]));
                float w1 = __expf(lrelu(xn + e_att[e1]));
                float w2 = __expf(lrelu(xn + e_att[e2]));
                float w3 = __expf(lrelu(xn + e_att[e3]));
                float v0 = bf2f(e_feat[(size_t)e0 * 64 + lane]) * w0;
                float v1 = bf2f(e_feat[(size_t)e1 * 64 + lane]) * w1;
                float v2 = bf2f(e_feat[(size_t)e2 * 64 + lane]) * w2;
                float v3 = bf2f(e_feat[(size_t)e3 * 64 + lane]) * w3;
                sw += w0 + w1 + w2 + w3;
                s  += v0 + v1 + v2 + v3;
                sq += v0 * v0 + v1 * v1 + v2 * v2 + v3 * v3;
                mx = fmaxf(fmaxf(mx, v0), fmaxf(fmaxf(v1, v2), v3));
                mn = fminf(fminf(mn, v0), fminf(fminf(v1, v2), v3));
            }
            for (; t < deg; t++) {
                int e = csr[start + t];
                float w = __expf(lrelu(xn + e_att[e]));
                float v = bf2f(e_feat[(size_t)e * 64 + lane]) * w;
                sw += w; s += v; sq += v * v;
                mx = fmaxf(mx, v); mn = fminf(mn, v);
            }
            float invD = 1.f / (sw + 1e-16f);
            float dc = (float)(deg > 0 ? deg : 1);
            float mean = s * invD / dc;
            float sqm  = sq * invD * invD / dc;
            float stdv = sqrtf(fmaxf(sqm - mean * mean, 0.f) + 1e-12f);
            unsigned short* row = &scat[j * 264];
            row[lane]       = f2bf(mean);
            row[64 + lane]  = f2bf(deg > 0 ? mx * invD : 0.f);
            row[128 + lane] = f2bf(deg > 0 ? mn * invD : 0.f);
            row[192 + lane] = f2bf(stdv);
        }
        __syncthreads();
        // ---- phase B: 8 MFMAs (K=256), A from LDS, B from registers ----
        f32x4 acc = {0.f, 0.f, 0.f, 0.f};
        #pragma unroll
        for (int s = 0; s < 8; s++) {
            bf16x8 a = *(const bf16x8*)&scat[nn * 264 + 32 * s + quad * 8];
            acc = __builtin_amdgcn_mfma_f32_16x16x32_bf16(a, wfrag[s], acc, 0, 0, 0);
        }
        // epilogue: lane holds nodes base+4*quad+r (r=0..3) for channel wave*16+nn
        int4 mc4 = *(const int4*)&mcount[base + 4 * quad];
        float h0 = lrelu(acc[0] + bias);
        float h1 = lrelu(acc[1] + bias);
        float h2 = lrelu(acc[2] + bias);
        float h3 = lrelu(acc[3] + bias);
        pool += h0 + h1 + h2 + h3;
        pmac += (float)mc4.x * h0 + (float)mc4.y * h1 + (float)mc4.z * h2 + (float)mc4.w * h3;
    }
    // reduce across the 4 quad-groups (same channel), then one atomic per channel
    pool += __shfl_xor(pool, 16); pool += __shfl_xor(pool, 32);
    pmac += __shfl_xor(pmac, 16); pmac += __shfl_xor(pmac, 32);
    if (quad == 0) {
        atomicAdd(&sum_all[wave * 16 + nn], pool);
        atomicAdd(&sum_mac[wave * 16 + nn], pmac);
    }
}

// ---------- tiny MLP head ----------
__global__ __launch_bounds__(256) void k_final(
    const float* __restrict__ sum_all, const float* __restrict__ sum_mac,
    const float* __restrict__ Wm1, const float* __restrict__ bm1,
    const float* __restrict__ Wm2, const float* __restrict__ bm2,
    const float* __restrict__ Wm3, const float* __restrict__ bm3,
    float* __restrict__ out)
{
    __shared__ float spool[128];
    __shared__ float z1[64];
    __shared__ float z2[32];
    if (threadIdx.x < 64) {
        spool[threadIdx.x]      = sum_mac[threadIdx.x] / (float)N_MACRO;
        spool[64 + threadIdx.x] = sum_all[threadIdx.x] / (float)N_NODES;
    }
    __syncthreads();
    if (threadIdx.x < 64) {
        int j = threadIdx.x;
        float a = bm1[j];
        #pragma unroll 4
        for (int k = 0; k < 128; k++) a += spool[k] * Wm1[k * 64 + j];
        z1[j] = lrelu(a);
    }
    __syncthreads();
    if (threadIdx.x < 32) {
        int j = threadIdx.x;
        float a = bm2[j];
        #pragma unroll 4
        for (int k = 0; k < 64; k++) a += z1[k] * Wm2[k * 32 + j];
        z2[j] = lrelu(a);
    }
    __syncthreads();
    if (threadIdx.x == 0) {
        float a = bm3[0];
        #pragma unroll
        for (int k = 0; k < 32; k++) a += z2[k] * Wm3[k];
        out[0] = a;
    }
}

// ---------- launch ----------
extern "C" void kernel_launch(void* const* d_in, const int* in_sizes, int n_in,
                              void* d_out, int out_size, void* d_ws, size_t ws_size,
                              hipStream_t stream)
{
    const float* x        = (const float*)d_in[0];
    const float* fake_pos = (const float*)d_in[1];
    const int*   edge     = (const int*)d_in[2];
    const float* pinf     = (const float*)d_in[3];
    const int*   macro    = (const int*)d_in[4];
    const float* W1    = (const float*)d_in[5];
    const float* b1    = (const float*)d_in[6];
    const float* Wpin  = (const float*)d_in[7];
    const float* att   = (const float*)d_in[8];
    const float* Wpost = (const float*)d_in[9];
    const float* bpost = (const float*)d_in[10];
    const float* Wm1   = (const float*)d_in[11];
    const float* bm1   = (const float*)d_in[12];
    const float* Wm2   = (const float*)d_in[13];
    const float* bm2   = (const float*)d_in[14];
    const float* Wm3   = (const float*)d_in[15];
    const float* bm3   = (const float*)d_in[16];
    float* out = (float*)d_out;

    float* ws = (float*)d_ws;
    // layout (4-byte units); zero region = [0, 700128)
    float*    ismacro = ws;                         //   200,000
    float*    sum_all = ws + 200000;                //        64
    float*    sum_mac = ws + 200064;                //        64
    int*      mcount  = (int*)(ws + 200128);        //   200,000
    int*      cnt     = (int*)(ws + 400128);        //   300,000
    // end zero region (700,128)
    int*      row_ptr  = (int*)(ws + 700128);       //   300,001
    int*      partials = (int*)(ws + 1000132);      //       300
    float*    va       = ws + 1000432;              //        40
    int*      rank_n   = (int*)(ws + 1000472);      // 1,000,000
    int*      rank_e   = (int*)(ws + 2000472);      // 1,000,000
    int*      csr      = (int*)(ws + 3000472);      // 2,000,000
    ushort4*  pfh      = (ushort4*)(ws + 5000472);  // 1M x 8B = 2,000,000 units (16B-aligned)
    float*    e_att    = ws + 7000472;              //   100,000
    float*    xn_att   = ws + 7100472;              //   200,000
    unsigned short* h      = (unsigned short*)(ws + 7300472);  // 6.4M ushort (3.2M units)
    unsigned short* e_feat = (unsigned short*)(ws + 10500472); // 6.4M ushort (3.2M units)
    // total: 13,700,472 units ~= 54.8 MB

    const int* nidx = edge;
    const int* hidx = edge + NNZ;

    fill_f32<<<1024, 256, 0, stream>>>(ws, 700128LL, 0.f);
    k_ismacro<<<2, 256, 0, stream>>>(macro, ismacro, mcount);
    k_count<<<2048, 256, 0, stream>>>(nidx, hidx, cnt, rank_n, rank_e);
    k_va<<<1, 64, 0, stream>>>(W1, b1, att, va);
    k_h<<<2048, 256, 0, stream>>>(x, fake_pos, ismacro, va, h, xn_att);
    k_scan1<<<NB_SCAN, 256, 0, stream>>>(cnt, row_ptr, partials);
    k_scan2<<<1, 512, 0, stream>>>(partials);
    k_scan3<<<NB_SCAN, 256, 0, stream>>>(row_ptr, partials);
    k_scatter<<<2048, 256, 0, stream>>>(nidx, hidx, row_ptr, rank_n, rank_e,
                                        (const float4*)pinf, csr, pfh);
    k_he_agg<<<2048, 256, 0, stream>>>(row_ptr, csr, pfh, W1, Wpin, b1, att, h, e_feat, e_att);
    k_fused<<<2048, 256, 0, stream>>>(row_ptr, csr, xn_att, e_att, e_feat, Wpost, bpost,
                                      mcount, sum_all, sum_mac);
    k_final<<<1, 256, 0, stream>>>(sum_all, sum_mac, Wm1, bm1, Wm2, bm2, Wm3, bm3, out);
}

// Round 11
// 499.280 us; speedup vs baseline: 5.1477x; 1.1074x over previous
//
#include <hip/hip_runtime.h>
#include <math.h>

#define N_NODES 200000
#define N_HE    100000
#define NNZ     1000000
#define F_RAW   29
#define N_MACRO 512
#define SLOPE   0.1f
#define L_TOTAL (N_NODES + N_HE)   // 300000 combined counters
#define NB_SCAN 293                // ceil(300000/1024)

typedef __attribute__((ext_vector_type(8))) short bf16x8;
typedef __attribute__((ext_vector_type(4))) float f32x4;

__device__ __forceinline__ float lrelu(float v) { return v >= 0.f ? v : SLOPE * v; }
__device__ __forceinline__ float bf2f(unsigned short u) { return __uint_as_float(((unsigned)u) << 16); }
__device__ __forceinline__ unsigned short f2bf(float f) {
    unsigned u = __float_as_uint(f);
    unsigned r = u + 0x7FFFu + ((u >> 16) & 1u);   // RNE
    return (unsigned short)(r >> 16);
}
__device__ __forceinline__ float bflo(unsigned u) { return __uint_as_float(u << 16); }
__device__ __forceinline__ float bfhi(unsigned u) { return __uint_as_float(u & 0xffff0000u); }

// ---------- fills ----------
__global__ __launch_bounds__(256) void fill_f32(float* p, long long n, float v) {
    long long i = (long long)blockIdx.x * blockDim.x + threadIdx.x;
    long long st = (long long)gridDim.x * blockDim.x;
    for (; i < n; i += st) p[i] = v;
}

__global__ __launch_bounds__(256) void k_ismacro(const int* __restrict__ mi,
                                                 float* __restrict__ ismacro, int* __restrict__ mcount) {
    int i = blockIdx.x * blockDim.x + threadIdx.x;
    if (i < N_MACRO) {
        ismacro[mi[i]] = 1.0f;
        atomicAdd(&mcount[mi[i]], 1);
    }
}

// ---------- va[k] = W1[k,:]·att[:64], va[32] = b1·att[:64] ----------
__global__ __launch_bounds__(64) void k_va(const float* __restrict__ W1, const float* __restrict__ b1,
                                           const float* __restrict__ att, float* __restrict__ va) {
    int t = threadIdx.x;
    if (t < 32) {
        float a = 0.f;
        for (int c = 0; c < 64; c++) a += W1[t * 64 + c] * att[c];
        va[t] = a;
    } else if (t == 32) {
        float a = 0.f;
        for (int c = 0; c < 64; c++) a += b1[c] * att[c];
        va[32] = a;
    }
}

// ---------- build h rows (32 bf16) + xn_att ----------
__global__ __launch_bounds__(256) void k_h(
    const float* __restrict__ x, const float* __restrict__ fp,
    const float* __restrict__ ismacro, const float* __restrict__ va,
    unsigned short* __restrict__ h, float* __restrict__ xn_att)
{
    const int lane = threadIdx.x & 63;
    const int half = lane >> 5, k = lane & 31;
    int wid = (blockIdx.x * blockDim.x + threadIdx.x) >> 6;
    int nw = (gridDim.x * blockDim.x) >> 6;
    float vak = va[k];
    float c0 = va[32];
    for (int base = wid * 2; base < N_NODES; base += nw * 2) {
        int n = base + half;
        float v;
        if (k < 29)       v = x[(size_t)n * F_RAW + k];
        else if (k == 29) v = fp[2 * n];
        else if (k == 30) v = fp[2 * n + 1];
        else              v = ismacro[n];
        h[(size_t)n * 32 + k] = f2bf(v);
        float r = v * vak;
        #pragma unroll
        for (int o = 16; o > 0; o >>= 1) r += __shfl_xor(r, o, 32);
        if (k == 0) xn_att[n] = r + c0;
    }
}

// ---------- counts + per-pin ranks (atomicAdd old value) ----------
__global__ __launch_bounds__(256) void k_count(
    const int* __restrict__ nidx, const int* __restrict__ hidx,
    int* __restrict__ cnt, int* __restrict__ rank_n, int* __restrict__ rank_e)
{
    int i = blockIdx.x * blockDim.x + threadIdx.x;
    int st = gridDim.x * blockDim.x;
    for (int p = i; p < NNZ; p += st) {
        rank_n[p] = atomicAdd(&cnt[nidx[p]], 1);
        rank_e[p] = atomicAdd(&cnt[N_NODES + hidx[p]], 1);
    }
}

// ---------- scan of cnt (length L_TOTAL) -> row_ptr ----------
__global__ __launch_bounds__(256) void k_scan1(const int* __restrict__ cnt,
                                               int* __restrict__ row_ptr, int* __restrict__ partials)
{
    __shared__ int sA[256], sB[256];
    const int t = threadIdx.x;
    const int base = blockIdx.x * 1024 + t * 4;
    int v0 = base + 0 < L_TOTAL ? cnt[base + 0] : 0;
    int v1 = base + 1 < L_TOTAL ? cnt[base + 1] : 0;
    int v2 = base + 2 < L_TOTAL ? cnt[base + 2] : 0;
    int v3 = base + 3 < L_TOTAL ? cnt[base + 3] : 0;
    sA[t] = v0 + v1 + v2 + v3;
    __syncthreads();
    int* src = sA; int* dst = sB;
    for (int off = 1; off < 256; off <<= 1) {
        int v = src[t];
        if (t >= off) v += src[t - off];
        dst[t] = v;
        __syncthreads();
        int* tmp = src; src = dst; dst = tmp;
    }
    int excl = t > 0 ? src[t - 1] : 0;
    if (base + 0 < L_TOTAL) row_ptr[base + 0] = excl;
    if (base + 1 < L_TOTAL) row_ptr[base + 1] = excl + v0;
    if (base + 2 < L_TOTAL) row_ptr[base + 2] = excl + v0 + v1;
    if (base + 3 < L_TOTAL) row_ptr[base + 3] = excl + v0 + v1 + v2;
    if (t == 255) partials[blockIdx.x] = src[255];
}

__global__ __launch_bounds__(512) void k_scan2(int* __restrict__ partials)
{
    __shared__ int sA[512], sB[512];
    const int t = threadIdx.x;
    sA[t] = t < NB_SCAN ? partials[t] : 0;
    __syncthreads();
    int* src = sA; int* dst = sB;
    for (int off = 1; off < 512; off <<= 1) {
        int v = src[t];
        if (t >= off) v += src[t - off];
        dst[t] = v;
        __syncthreads();
        int* tmp = src; src = dst; dst = tmp;
    }
    if (t < NB_SCAN) partials[t] = t > 0 ? src[t - 1] : 0;
    if (t == 0) partials[NB_SCAN] = src[511];
}

__global__ __launch_bounds__(256) void k_scan3(int* __restrict__ row_ptr, const int* __restrict__ partials)
{
    const int base = blockIdx.x * 1024 + threadIdx.x * 4;
    int add = partials[blockIdx.x];
    #pragma unroll
    for (int k = 0; k < 4; k++)
        if (base + k < L_TOTAL) row_ptr[base + k] += add;
    if (blockIdx.x == 0 && threadIdx.x == 0) row_ptr[L_TOTAL] = partials[NB_SCAN];
}

// ---------- atomic-free scatter: csr + bf16 pinf into he-slot order ----------
__global__ __launch_bounds__(256) void k_scatter(
    const int* __restrict__ nidx, const int* __restrict__ hidx,
    const int* __restrict__ row_ptr,
    const int* __restrict__ rank_n, const int* __restrict__ rank_e,
    const float4* __restrict__ pf4, int* __restrict__ csr, ushort4* __restrict__ pfh)
{
    int i = blockIdx.x * blockDim.x + threadIdx.x;
    int st = gridDim.x * blockDim.x;
    for (int p = i; p < NNZ; p += st) {
        int n = nidx[p], e = hidx[p];
        csr[row_ptr[n] + rank_n[p]] = e;
        int pe = row_ptr[N_NODES + e] + rank_e[p];  // absolute slot (>= NNZ)
        csr[pe] = n;
        float4 q = pf4[p];
        ushort4 r;
        r.x = f2bf(q.x); r.y = f2bf(q.y); r.z = f2bf(q.z); r.w = f2bf(q.w);
        pfh[pe - NNZ] = r;
    }
}

// ---------- he-side: quarter-wave h-row gathers + coalesced bf16 pinf, matvec W1 ----------
__global__ __launch_bounds__(256) void k_he_agg(
    const int* __restrict__ row_ptr, const int* __restrict__ csr,
    const ushort4* __restrict__ pfh,
    const float* __restrict__ W1, const float* __restrict__ Wpin,
    const float* __restrict__ b1, const float* __restrict__ att,
    const unsigned short* __restrict__ h,
    unsigned short* __restrict__ e_feat, float* __restrict__ e_att)
{
    __shared__ float sW1[32 * 64];
    __shared__ float sWp[4 * 64];
    __shared__ float sb1[64];
    for (int i = threadIdx.x; i < 32 * 64; i += 256) sW1[i] = W1[i];
    for (int i = threadIdx.x; i < 4 * 64; i += 256) sWp[i] = Wpin[i];
    if (threadIdx.x < 64) sb1[threadIdx.x] = b1[threadIdx.x];
    __syncthreads();
    const int lane = threadIdx.x & 63;
    const int g  = lane >> 4;    // 0..3: pin group
    const int gl = lane & 15;    // k-pair index: k = 2gl, 2gl+1
    float att2 = att[64 + lane];
    int wid = (blockIdx.x * blockDim.x + threadIdx.x) >> 6;
    int nw = (gridDim.x * blockDim.x) >> 6;
    for (int e = wid; e < N_HE; e += nw) {
        int start = row_ptr[N_NODES + e];
        int deg = row_ptr[N_NODES + e + 1] - start;
        // gather h rows: each 16-lane group loads one 64B row (uint/lane), 4 pins in flight
        float hx = 0.f, hy = 0.f;
        {
            int t = g;
            for (; t + 4 < deg; t += 8) {
                int n0 = csr[start + t];
                int n1 = csr[start + t + 4];
                unsigned u0 = ((const unsigned*)&h[(size_t)n0 * 32])[gl];
                unsigned u1 = ((const unsigned*)&h[(size_t)n1 * 32])[gl];
                hx += bflo(u0) + bflo(u1);
                hy += bfhi(u0) + bfhi(u1);
            }
            for (; t < deg; t += 4) {
                int n = csr[start + t];
                unsigned u = ((const unsigned*)&h[(size_t)n * 32])[gl];
                hx += bflo(u); hy += bfhi(u);
            }
        }
        hx += __shfl_xor(hx, 16); hy += __shfl_xor(hy, 16);
        hx += __shfl_xor(hx, 32); hy += __shfl_xor(hy, 32);
        // coalesced bf16 pinf sums
        float p0 = 0.f, p1 = 0.f, p2 = 0.f, p3 = 0.f;
        for (int t = lane; t < deg; t += 64) {
            ushort4 r = pfh[start - NNZ + t];
            p0 += bf2f(r.x); p1 += bf2f(r.y); p2 += bf2f(r.z); p3 += bf2f(r.w);
        }
        #pragma unroll
        for (int o = 32; o > 0; o >>= 1) {
            p0 += __shfl_xor(p0, o, 64); p1 += __shfl_xor(p1, o, 64);
            p2 += __shfl_xor(p2, o, 64); p3 += __shfl_xor(p3, o, 64);
        }
        float acc = (float)deg * sb1[lane]
                  + p0 * sWp[lane] + p1 * sWp[64 + lane]
                  + p2 * sWp[128 + lane] + p3 * sWp[192 + lane];
        #pragma unroll
        for (int kk = 0; kk < 16; kk++) {
            float hvx = __shfl(hx, kk, 64);
            float hvy = __shfl(hy, kk, 64);
            acc += hvx * sW1[(2 * kk) * 64 + lane] + hvy * sW1[(2 * kk + 1) * 64 + lane];
        }
        float d = (float)(deg > 0 ? deg : 1);
        float v = acc / d;
        e_feat[(size_t)e * 64 + lane] = f2bf(v);
        float r = v * att2;
        #pragma unroll
        for (int o = 32; o > 0; o >>= 1) r += __shfl_down(r, o, 64);
        if (lane == 0) e_att[e] = r;
    }
}

// ---------- fused softmax+PNA (half-wave pin split) + MFMA post-GEMM + pools ----------
// Phase A: 4 nodes/wave; the two 32-lane halves process even/odd pins of the SAME
// node concurrently (e_feat row = 64B bf16 = 32 lanes x ushort2; 2 channels/lane).
// Halves combine via shfl_xor(32) (sum/max/min - exact). Phase B unchanged from
// R10: 8x mfma_f32_16x16x32_bf16, A from LDS (scat[16][264] bf16), B = W in regs.
__global__ __launch_bounds__(256, 4) void k_fused(
    const int* __restrict__ row_ptr, const int* __restrict__ csr,
    const float* __restrict__ xn_att, const float* __restrict__ e_att,
    const unsigned short* __restrict__ e_feat,
    const float* __restrict__ Wpost, const float* __restrict__ bpost,
    const int* __restrict__ mcount,
    float* __restrict__ sum_all, float* __restrict__ sum_mac)
{
    __shared__ __align__(16) unsigned short scat[16 * 264];   // 8448 B
    const int lane = threadIdx.x & 63;
    const int wave = threadIdx.x >> 6;
    const int half = lane >> 5;     // pin parity
    const int c2   = lane & 31;     // channel pair: channels 2c2, 2c2+1
    const int quad = lane >> 4;     // phase B
    const int nn   = lane & 15;     // phase B
    // B fragments: lane holds W[k = 32s + quad*8 + j][c = wave*16 + nn], j=0..7
    bf16x8 wfrag[8];
    #pragma unroll
    for (int s = 0; s < 8; s++) {
        bf16x8 w;
        #pragma unroll
        for (int j = 0; j < 8; j++)
            w[j] = (short)f2bf(Wpost[(size_t)(32 * s + quad * 8 + j) * 64 + wave * 16 + nn]);
        wfrag[s] = w;
    }
    float bias = bpost[wave * 16 + nn];
    float pool = 0.f, pmac = 0.f;
    const int nbatches = N_NODES / 16;  // 12500
    for (int b = blockIdx.x; b < nbatches; b += gridDim.x) {
        const int base = b * 16;
        __syncthreads();
        // ---- phase A ----
        for (int i = 0; i < 4; i++) {
            int j = wave * 4 + i;
            int n = base + j;
            int start = row_ptr[n];
            int deg = row_ptr[n + 1] - start;
            float xn = xn_att[n];
            float sw = 0.f;
            float sx = 0.f, sy = 0.f, qx = 0.f, qy = 0.f;
            float mxx = -INFINITY, mxy = -INFINITY, mnx = INFINITY, mny = INFINITY;
            int t = half;
            for (; t + 2 < deg; t += 4) {
                int e0 = csr[start + t];
                int e1 = csr[start + t + 2];
                float w0 = __expf(lrelu(xn + e_att[e0]));
                float w1 = __expf(lrelu(xn + e_att[e1]));
                unsigned u0 = ((const unsigned*)&e_feat[(size_t)e0 * 64])[c2];
                unsigned u1 = ((const unsigned*)&e_feat[(size_t)e1 * 64])[c2];
                float v0x = bflo(u0) * w0, v0y = bfhi(u0) * w0;
                float v1x = bflo(u1) * w1, v1y = bfhi(u1) * w1;
                sw += w0 + w1;
                sx += v0x + v1x; sy += v0y + v1y;
                qx += v0x * v0x + v1x * v1x; qy += v0y * v0y + v1y * v1y;
                mxx = fmaxf(mxx, fmaxf(v0x, v1x)); mxy = fmaxf(mxy, fmaxf(v0y, v1y));
                mnx = fminf(mnx, fminf(v0x, v1x)); mny = fminf(mny, fminf(v0y, v1y));
            }
            for (; t < deg; t += 2) {
                int e = csr[start + t];
                float w = __expf(lrelu(xn + e_att[e]));
                unsigned u = ((const unsigned*)&e_feat[(size_t)e * 64])[c2];
                float vx = bflo(u) * w, vy = bfhi(u) * w;
                sw += w; sx += vx; sy += vy; qx += vx * vx; qy += vy * vy;
                mxx = fmaxf(mxx, vx); mxy = fmaxf(mxy, vy);
                mnx = fminf(mnx, vx); mny = fminf(mny, vy);
            }
            // combine the two halves (exact: sums add, max/min merge)
            sw  += __shfl_xor(sw, 32);
            sx  += __shfl_xor(sx, 32);  sy += __shfl_xor(sy, 32);
            qx  += __shfl_xor(qx, 32);  qy += __shfl_xor(qy, 32);
            mxx = fmaxf(mxx, __shfl_xor(mxx, 32)); mxy = fmaxf(mxy, __shfl_xor(mxy, 32));
            mnx = fminf(mnx, __shfl_xor(mnx, 32)); mny = fminf(mny, __shfl_xor(mny, 32));
            float invD = 1.f / (sw + 1e-16f);
            float dc = (float)(deg > 0 ? deg : 1);
            float meanx = sx * invD / dc, meany = sy * invD / dc;
            float sqmx = qx * invD * invD / dc, sqmy = qy * invD * invD / dc;
            float stdx = sqrtf(fmaxf(sqmx - meanx * meanx, 0.f) + 1e-12f);
            float stdy = sqrtf(fmaxf(sqmy - meany * meany, 0.f) + 1e-12f);
            ushort2* row = (ushort2*)&scat[j * 264];
            if (half == 0) {
                ushort2 a; a.x = f2bf(meanx); a.y = f2bf(meany);
                row[c2] = a;
                ushort2 bmax; bmax.x = f2bf(deg > 0 ? mxx * invD : 0.f);
                bmax.y = f2bf(deg > 0 ? mxy * invD : 0.f);
                row[32 + c2] = bmax;
            } else {
                ushort2 bmin; bmin.x = f2bf(deg > 0 ? mnx * invD : 0.f);
                bmin.y = f2bf(deg > 0 ? mny * invD : 0.f);
                row[64 + c2] = bmin;
                ushort2 bstd; bstd.x = f2bf(stdx); bstd.y = f2bf(stdy);
                row[96 + c2] = bstd;
            }
        }
        __syncthreads();
        // ---- phase B: 8 MFMAs (K=256), A from LDS, B from registers ----
        f32x4 acc = {0.f, 0.f, 0.f, 0.f};
        #pragma unroll
        for (int s = 0; s < 8; s++) {
            bf16x8 a = *(const bf16x8*)&scat[nn * 264 + 32 * s + quad * 8];
            acc = __builtin_amdgcn_mfma_f32_16x16x32_bf16(a, wfrag[s], acc, 0, 0, 0);
        }
        // epilogue: lane holds nodes base+4*quad+r (r=0..3) for channel wave*16+nn
        int4 mc4 = *(const int4*)&mcount[base + 4 * quad];
        float h0 = lrelu(acc[0] + bias);
        float h1 = lrelu(acc[1] + bias);
        float h2 = lrelu(acc[2] + bias);
        float h3 = lrelu(acc[3] + bias);
        pool += h0 + h1 + h2 + h3;
        pmac += (float)mc4.x * h0 + (float)mc4.y * h1 + (float)mc4.z * h2 + (float)mc4.w * h3;
    }
    // reduce across the 4 quad-groups (same channel), then one atomic per channel
    pool += __shfl_xor(pool, 16); pool += __shfl_xor(pool, 32);
    pmac += __shfl_xor(pmac, 16); pmac += __shfl_xor(pmac, 32);
    if (quad == 0) {
        atomicAdd(&sum_all[wave * 16 + nn], pool);
        atomicAdd(&sum_mac[wave * 16 + nn], pmac);
    }
}

// ---------- tiny MLP head ----------
__global__ __launch_bounds__(256) void k_final(
    const float* __restrict__ sum_all, const float* __restrict__ sum_mac,
    const float* __restrict__ Wm1, const float* __restrict__ bm1,
    const float* __restrict__ Wm2, const float* __restrict__ bm2,
    const float* __restrict__ Wm3, const float* __restrict__ bm3,
    float* __restrict__ out)
{
    __shared__ float spool[128];
    __shared__ float z1[64];
    __shared__ float z2[32];
    if (threadIdx.x < 64) {
        spool[threadIdx.x]      = sum_mac[threadIdx.x] / (float)N_MACRO;
        spool[64 + threadIdx.x] = sum_all[threadIdx.x] / (float)N_NODES;
    }
    __syncthreads();
    if (threadIdx.x < 64) {
        int j = threadIdx.x;
        float a = bm1[j];
        #pragma unroll 4
        for (int k = 0; k < 128; k++) a += spool[k] * Wm1[k * 64 + j];
        z1[j] = lrelu(a);
    }
    __syncthreads();
    if (threadIdx.x < 32) {
        int j = threadIdx.x;
        float a = bm2[j];
        #pragma unroll 4
        for (int k = 0; k < 64; k++) a += z1[k] * Wm2[k * 32 + j];
        z2[j] = lrelu(a);
    }
    __syncthreads();
    if (threadIdx.x == 0) {
        float a = bm3[0];
        #pragma unroll
        for (int k = 0; k < 32; k++) a += z2[k] * Wm3[k];
        out[0] = a;
    }
}

// ---------- launch ----------
extern "C" void kernel_launch(void* const* d_in, const int* in_sizes, int n_in,
                              void* d_out, int out_size, void* d_ws, size_t ws_size,
                              hipStream_t stream)
{
    const float* x        = (const float*)d_in[0];
    const float* fake_pos = (const float*)d_in[1];
    const int*   edge     = (const int*)d_in[2];
    const float* pinf     = (const float*)d_in[3];
    const int*   macro    = (const int*)d_in[4];
    const float* W1    = (const float*)d_in[5];
    const float* b1    = (const float*)d_in[6];
    const float* Wpin  = (const float*)d_in[7];
    const float* att   = (const float*)d_in[8];
    const float* Wpost = (const float*)d_in[9];
    const float* bpost = (const float*)d_in[10];
    const float* Wm1   = (const float*)d_in[11];
    const float* bm1   = (const float*)d_in[12];
    const float* Wm2   = (const float*)d_in[13];
    const float* bm2   = (const float*)d_in[14];
    const float* Wm3   = (const float*)d_in[15];
    const float* bm3   = (const float*)d_in[16];
    float* out = (float*)d_out;

    float* ws = (float*)d_ws;
    // layout (4-byte units); zero region = [0, 700128)
    float*    ismacro = ws;                         //   200,000
    float*    sum_all = ws + 200000;                //        64
    float*    sum_mac = ws + 200064;                //        64
    int*      mcount  = (int*)(ws + 200128);        //   200,000
    int*      cnt     = (int*)(ws + 400128);        //   300,000
    // end zero region (700,128)
    int*      row_ptr  = (int*)(ws + 700128);       //   300,001
    int*      partials = (int*)(ws + 1000132);      //       300
    float*    va       = ws + 1000432;              //        40
    int*      rank_n   = (int*)(ws + 1000472);      // 1,000,000
    int*      rank_e   = (int*)(ws + 2000472);      // 1,000,000
    int*      csr      = (int*)(ws + 3000472);      // 2,000,000
    ushort4*  pfh      = (ushort4*)(ws + 5000472);  // 1M x 8B = 2,000,000 units (16B-aligned)
    float*    e_att    = ws + 7000472;              //   100,000
    float*    xn_att   = ws + 7100472;              //   200,000
    unsigned short* h      = (unsigned short*)(ws + 7300472);  // 6.4M ushort (3.2M units)
    unsigned short* e_feat = (unsigned short*)(ws + 10500472); // 6.4M ushort (3.2M units)
    // total: 13,700,472 units ~= 54.8 MB

    const int* nidx = edge;
    const int* hidx = edge + NNZ;

    fill_f32<<<1024, 256, 0, stream>>>(ws, 700128LL, 0.f);
    k_ismacro<<<2, 256, 0, stream>>>(macro, ismacro, mcount);
    k_count<<<2048, 256, 0, stream>>>(nidx, hidx, cnt, rank_n, rank_e);
    k_va<<<1, 64, 0, stream>>>(W1, b1, att, va);
    k_h<<<2048, 256, 0, stream>>>(x, fake_pos, ismacro, va, h, xn_att);
    k_scan1<<<NB_SCAN, 256, 0, stream>>>(cnt, row_ptr, partials);
    k_scan2<<<1, 512, 0, stream>>>(partials);
    k_scan3<<<NB_SCAN, 256, 0, stream>>>(row_ptr, partials);
    k_scatter<<<2048, 256, 0, stream>>>(nidx, hidx, row_ptr, rank_n, rank_e,
                                        (const float4*)pinf, csr, pfh);
    k_he_agg<<<2048, 256, 0, stream>>>(row_ptr, csr, pfh, W1, Wpin, b1, att, h, e_feat, e_att);
    k_fused<<<2048, 256, 0, stream>>>(row_ptr, csr, xn_att, e_att, e_feat, Wpost, bpost,
                                      mcount, sum_all, sum_mac);
    k_final<<<1, 256, 0, stream>>>(sum_all, sum_mac, Wm1, bm1, Wm2, bm2, Wm3, bm3, out);
}

// Round 12
// 473.957 us; speedup vs baseline: 5.4227x; 1.0534x over previous
//
#include <hip/hip_runtime.h>
#include <math.h>

#define N_NODES 200000
#define N_HE    100000
#define NNZ     1000000
#define F_RAW   29
#define N_MACRO 512
#define SLOPE   0.1f
#define L_TOTAL (N_NODES + N_HE)   // 300000 combined counters
#define NB_SCAN 293                // ceil(300000/1024)

typedef __attribute__((ext_vector_type(8))) short bf16x8;
typedef __attribute__((ext_vector_type(4))) float f32x4;

__device__ __forceinline__ float lrelu(float v) { return v >= 0.f ? v : SLOPE * v; }
__device__ __forceinline__ float bf2f(unsigned short u) { return __uint_as_float(((unsigned)u) << 16); }
__device__ __forceinline__ unsigned short f2bf(float f) {
    unsigned u = __float_as_uint(f);
    unsigned r = u + 0x7FFFu + ((u >> 16) & 1u);   // RNE
    return (unsigned short)(r >> 16);
}
__device__ __forceinline__ float bflo(unsigned u) { return __uint_as_float(u << 16); }
__device__ __forceinline__ float bfhi(unsigned u) { return __uint_as_float(u & 0xffff0000u); }

// ---------- fill ----------
__global__ __launch_bounds__(256) void fill_f32(float* p, long long n, float v) {
    long long i = (long long)blockIdx.x * blockDim.x + threadIdx.x;
    long long st = (long long)gridDim.x * blockDim.x;
    for (; i < n; i += st) p[i] = v;
}

// ---------- fused pre-pass: va (block 0) + ismacro (blocks 1-2) + count (blocks 3+) ----------
__global__ __launch_bounds__(256) void k_pre(
    const int* __restrict__ mi, float* __restrict__ ismacro, int* __restrict__ mcount,
    const float* __restrict__ W1, const float* __restrict__ b1,
    const float* __restrict__ att, float* __restrict__ va,
    const int* __restrict__ nidx, const int* __restrict__ hidx,
    int* __restrict__ cnt, int* __restrict__ rank_n, int* __restrict__ rank_e)
{
    if (blockIdx.x == 0) {
        int t = threadIdx.x;
        if (t < 32) {
            float a = 0.f;
            for (int c = 0; c < 64; c++) a += W1[t * 64 + c] * att[c];
            va[t] = a;
        } else if (t == 32) {
            float a = 0.f;
            for (int c = 0; c < 64; c++) a += b1[c] * att[c];
            va[32] = a;
        }
    } else if (blockIdx.x <= 2) {
        int i = (blockIdx.x - 1) * 256 + threadIdx.x;
        if (i < N_MACRO) {
            ismacro[mi[i]] = 1.0f;
            atomicAdd(&mcount[mi[i]], 1);
        }
    } else {
        int i = (blockIdx.x - 3) * 256 + threadIdx.x;
        int st = (gridDim.x - 3) * 256;
        for (int p = i; p < NNZ; p += st) {
            rank_n[p] = atomicAdd(&cnt[nidx[p]], 1);
            rank_e[p] = atomicAdd(&cnt[N_NODES + hidx[p]], 1);
        }
    }
}

// ---------- scan of cnt (length L_TOTAL) -> row_ptr ----------
__global__ __launch_bounds__(256) void k_scan1(const int* __restrict__ cnt,
                                               int* __restrict__ row_ptr, int* __restrict__ partials)
{
    __shared__ int sA[256], sB[256];
    const int t = threadIdx.x;
    const int base = blockIdx.x * 1024 + t * 4;
    int v0 = base + 0 < L_TOTAL ? cnt[base + 0] : 0;
    int v1 = base + 1 < L_TOTAL ? cnt[base + 1] : 0;
    int v2 = base + 2 < L_TOTAL ? cnt[base + 2] : 0;
    int v3 = base + 3 < L_TOTAL ? cnt[base + 3] : 0;
    sA[t] = v0 + v1 + v2 + v3;
    __syncthreads();
    int* src = sA; int* dst = sB;
    for (int off = 1; off < 256; off <<= 1) {
        int v = src[t];
        if (t >= off) v += src[t - off];
        dst[t] = v;
        __syncthreads();
        int* tmp = src; src = dst; dst = tmp;
    }
    int excl = t > 0 ? src[t - 1] : 0;
    if (base + 0 < L_TOTAL) row_ptr[base + 0] = excl;
    if (base + 1 < L_TOTAL) row_ptr[base + 1] = excl + v0;
    if (base + 2 < L_TOTAL) row_ptr[base + 2] = excl + v0 + v1;
    if (base + 3 < L_TOTAL) row_ptr[base + 3] = excl + v0 + v1 + v2;
    if (t == 255) partials[blockIdx.x] = src[255];
}

__global__ __launch_bounds__(512) void k_scan2(int* __restrict__ partials)
{
    __shared__ int sA[512], sB[512];
    const int t = threadIdx.x;
    sA[t] = t < NB_SCAN ? partials[t] : 0;
    __syncthreads();
    int* src = sA; int* dst = sB;
    for (int off = 1; off < 512; off <<= 1) {
        int v = src[t];
        if (t >= off) v += src[t - off];
        dst[t] = v;
        __syncthreads();
        int* tmp = src; src = dst; dst = tmp;
    }
    if (t < NB_SCAN) partials[t] = t > 0 ? src[t - 1] : 0;
    if (t == 0) partials[NB_SCAN] = src[511];
}

__global__ __launch_bounds__(256) void k_scan3(int* __restrict__ row_ptr, const int* __restrict__ partials)
{
    const int base = blockIdx.x * 1024 + threadIdx.x * 4;
    int add = partials[blockIdx.x];
    #pragma unroll
    for (int k = 0; k < 4; k++)
        if (base + k < L_TOTAL) row_ptr[base + k] += add;
    if (blockIdx.x == 0 && threadIdx.x == 0) row_ptr[L_TOTAL] = partials[NB_SCAN];
}

// ---------- fused mid-pass: scatter (blocks 0..2047) + h build (blocks 2048..3071) ----------
// scatter: csr_n[slot]=he id; he-side one int4 record {node, pf01, pf23, 0} (single 16B sector).
__global__ __launch_bounds__(256) void k_mid(
    const int* __restrict__ nidx, const int* __restrict__ hidx,
    const int* __restrict__ row_ptr,
    const int* __restrict__ rank_n, const int* __restrict__ rank_e,
    const float4* __restrict__ pf4, int* __restrict__ csr_n, int4* __restrict__ rec,
    const float* __restrict__ x, const float* __restrict__ fp,
    const float* __restrict__ ismacro, const float* __restrict__ va,
    unsigned short* __restrict__ h, float* __restrict__ xn_att)
{
    if (blockIdx.x < 2048) {
        int i = blockIdx.x * 256 + threadIdx.x;
        int st = 2048 * 256;
        for (int p = i; p < NNZ; p += st) {
            int n = nidx[p], e = hidx[p];
            csr_n[row_ptr[n] + rank_n[p]] = e;
            int pe = row_ptr[N_NODES + e] + rank_e[p];  // absolute he slot (>= NNZ)
            float4 q = pf4[p];
            int4 r;
            r.x = n;
            r.y = (int)((unsigned)f2bf(q.x) | ((unsigned)f2bf(q.y) << 16));
            r.z = (int)((unsigned)f2bf(q.z) | ((unsigned)f2bf(q.w) << 16));
            r.w = 0;
            rec[pe - NNZ] = r;
        }
    } else {
        const int lane = threadIdx.x & 63;
        const int half = lane >> 5, k = lane & 31;
        int wid = ((blockIdx.x - 2048) * 256 + threadIdx.x) >> 6;
        int nw = (1024 * 256) >> 6;
        float vak = va[k];
        float c0 = va[32];
        for (int base = wid * 2; base < N_NODES; base += nw * 2) {
            int n = base + half;
            float v;
            if (k < 29)       v = x[(size_t)n * F_RAW + k];
            else if (k == 29) v = fp[2 * n];
            else if (k == 30) v = fp[2 * n + 1];
            else              v = ismacro[n];
            h[(size_t)n * 32 + k] = f2bf(v);
            float r = v * vak;
            #pragma unroll
            for (int o = 16; o > 0; o >>= 1) r += __shfl_xor(r, o, 32);
            if (k == 0) xn_att[n] = r + c0;
        }
    }
}

// ---------- he-side: 8-lane pin groups (8-16 rows in flight), merged rec reads ----------
__global__ __launch_bounds__(256) void k_he_agg(
    const int* __restrict__ row_ptr, const int4* __restrict__ rec,
    const float* __restrict__ W1, const float* __restrict__ Wpin,
    const float* __restrict__ b1, const float* __restrict__ att,
    const unsigned short* __restrict__ h,
    unsigned short* __restrict__ e_feat, float* __restrict__ e_att)
{
    __shared__ float sW1[32 * 64];
    __shared__ float sWp[4 * 64];
    __shared__ float sb1[64];
    for (int i = threadIdx.x; i < 32 * 64; i += 256) sW1[i] = W1[i];
    for (int i = threadIdx.x; i < 4 * 64; i += 256) sWp[i] = Wpin[i];
    if (threadIdx.x < 64) sb1[threadIdx.x] = b1[threadIdx.x];
    __syncthreads();
    const int lane = threadIdx.x & 63;
    const int g  = lane >> 3;    // pin group 0..7
    const int gl = lane & 7;     // channel quad: k = 4gl..4gl+3
    float att2 = att[64 + lane];
    int wid = (blockIdx.x * blockDim.x + threadIdx.x) >> 6;
    int nw = (gridDim.x * blockDim.x) >> 6;
    for (int e = wid; e < N_HE; e += nw) {
        int start = row_ptr[N_NODES + e];
        int deg = row_ptr[N_NODES + e + 1] - start;
        float h0 = 0.f, h1 = 0.f, h2 = 0.f, h3 = 0.f;
        float pa = 0.f, pb = 0.f;
        const int4* rbase = rec + (start - NNZ);
        int t = g;
        for (; t + 8 < deg; t += 16) {
            int4 rA = rbase[t];
            int4 rB = rbase[t + 8];
            ushort4 uA = *(const ushort4*)&h[(size_t)rA.x * 32 + 4 * gl];
            ushort4 uB = *(const ushort4*)&h[(size_t)rB.x * 32 + 4 * gl];
            h0 += bf2f(uA.x) + bf2f(uB.x);
            h1 += bf2f(uA.y) + bf2f(uB.y);
            h2 += bf2f(uA.z) + bf2f(uB.z);
            h3 += bf2f(uA.w) + bf2f(uB.w);
            unsigned pyA = (gl == 0) ? (unsigned)rA.y : ((gl == 1) ? (unsigned)rA.z : 0u);
            unsigned pyB = (gl == 0) ? (unsigned)rB.y : ((gl == 1) ? (unsigned)rB.z : 0u);
            pa += bflo(pyA) + bflo(pyB);
            pb += bfhi(pyA) + bfhi(pyB);
        }
        if (t < deg) {
            int4 r = rbase[t];
            ushort4 u = *(const ushort4*)&h[(size_t)r.x * 32 + 4 * gl];
            h0 += bf2f(u.x); h1 += bf2f(u.y); h2 += bf2f(u.z); h3 += bf2f(u.w);
            unsigned py = (gl == 0) ? (unsigned)r.y : ((gl == 1) ? (unsigned)r.z : 0u);
            pa += bflo(py); pb += bfhi(py);
        }
        // combine the 8 pin groups (lane bits 3..5)
        #pragma unroll
        for (int o = 8; o <= 32; o <<= 1) {
            h0 += __shfl_xor(h0, o); h1 += __shfl_xor(h1, o);
            h2 += __shfl_xor(h2, o); h3 += __shfl_xor(h3, o);
            pa += __shfl_xor(pa, o); pb += __shfl_xor(pb, o);
        }
        float p0 = __shfl(pa, 0, 64), p1 = __shfl(pb, 0, 64);
        float p2 = __shfl(pa, 1, 64), p3 = __shfl(pb, 1, 64);
        float acc = (float)deg * sb1[lane]
                  + p0 * sWp[lane] + p1 * sWp[64 + lane]
                  + p2 * sWp[128 + lane] + p3 * sWp[192 + lane];
        #pragma unroll
        for (int kk = 0; kk < 8; kk++) {
            float a0 = __shfl(h0, kk, 64), a1 = __shfl(h1, kk, 64);
            float a2 = __shfl(h2, kk, 64), a3 = __shfl(h3, kk, 64);
            acc += a0 * sW1[(4 * kk + 0) * 64 + lane] + a1 * sW1[(4 * kk + 1) * 64 + lane]
                 + a2 * sW1[(4 * kk + 2) * 64 + lane] + a3 * sW1[(4 * kk + 3) * 64 + lane];
        }
        float d = (float)(deg > 0 ? deg : 1);
        float v = acc / d;
        e_feat[(size_t)e * 64 + lane] = f2bf(v);
        float r = v * att2;
        #pragma unroll
        for (int o = 32; o > 0; o >>= 1) r += __shfl_down(r, o, 64);
        if (lane == 0) e_att[e] = r;
    }
}

// ---------- fused softmax+PNA (half-wave pin split) + MFMA post-GEMM + pools ----------
// (unchanged from R11 - verified at 144 us)
__global__ __launch_bounds__(256, 4) void k_fused(
    const int* __restrict__ row_ptr, const int* __restrict__ csr,
    const float* __restrict__ xn_att, const float* __restrict__ e_att,
    const unsigned short* __restrict__ e_feat,
    const float* __restrict__ Wpost, const float* __restrict__ bpost,
    const int* __restrict__ mcount,
    float* __restrict__ sum_all, float* __restrict__ sum_mac)
{
    __shared__ __align__(16) unsigned short scat[16 * 264];   // 8448 B
    const int lane = threadIdx.x & 63;
    const int wave = threadIdx.x >> 6;
    const int half = lane >> 5;     // pin parity
    const int c2   = lane & 31;     // channel pair: channels 2c2, 2c2+1
    const int quad = lane >> 4;     // phase B
    const int nn   = lane & 15;     // phase B
    bf16x8 wfrag[8];
    #pragma unroll
    for (int s = 0; s < 8; s++) {
        bf16x8 w;
        #pragma unroll
        for (int j = 0; j < 8; j++)
            w[j] = (short)f2bf(Wpost[(size_t)(32 * s + quad * 8 + j) * 64 + wave * 16 + nn]);
        wfrag[s] = w;
    }
    float bias = bpost[wave * 16 + nn];
    float pool = 0.f, pmac = 0.f;
    const int nbatches = N_NODES / 16;  // 12500
    for (int b = blockIdx.x; b < nbatches; b += gridDim.x) {
        const int base = b * 16;
        __syncthreads();
        for (int i = 0; i < 4; i++) {
            int j = wave * 4 + i;
            int n = base + j;
            int start = row_ptr[n];
            int deg = row_ptr[n + 1] - start;
            float xn = xn_att[n];
            float sw = 0.f;
            float sx = 0.f, sy = 0.f, qx = 0.f, qy = 0.f;
            float mxx = -INFINITY, mxy = -INFINITY, mnx = INFINITY, mny = INFINITY;
            int t = half;
            for (; t + 2 < deg; t += 4) {
                int e0 = csr[start + t];
                int e1 = csr[start + t + 2];
                float w0 = __expf(lrelu(xn + e_att[e0]));
                float w1 = __expf(lrelu(xn + e_att[e1]));
                unsigned u0 = ((const unsigned*)&e_feat[(size_t)e0 * 64])[c2];
                unsigned u1 = ((const unsigned*)&e_feat[(size_t)e1 * 64])[c2];
                float v0x = bflo(u0) * w0, v0y = bfhi(u0) * w0;
                float v1x = bflo(u1) * w1, v1y = bfhi(u1) * w1;
                sw += w0 + w1;
                sx += v0x + v1x; sy += v0y + v1y;
                qx += v0x * v0x + v1x * v1x; qy += v0y * v0y + v1y * v1y;
                mxx = fmaxf(mxx, fmaxf(v0x, v1x)); mxy = fmaxf(mxy, fmaxf(v0y, v1y));
                mnx = fminf(mnx, fminf(v0x, v1x)); mny = fminf(mny, fminf(v0y, v1y));
            }
            for (; t < deg; t += 2) {
                int e = csr[start + t];
                float w = __expf(lrelu(xn + e_att[e]));
                unsigned u = ((const unsigned*)&e_feat[(size_t)e * 64])[c2];
                float vx = bflo(u) * w, vy = bfhi(u) * w;
                sw += w; sx += vx; sy += vy; qx += vx * vx; qy += vy * vy;
                mxx = fmaxf(mxx, vx); mxy = fmaxf(mxy, vy);
                mnx = fminf(mnx, vx); mny = fminf(mny, vy);
            }
            sw  += __shfl_xor(sw, 32);
            sx  += __shfl_xor(sx, 32);  sy += __shfl_xor(sy, 32);
            qx  += __shfl_xor(qx, 32);  qy += __shfl_xor(qy, 32);
            mxx = fmaxf(mxx, __shfl_xor(mxx, 32)); mxy = fmaxf(mxy, __shfl_xor(mxy, 32));
            mnx = fminf(mnx, __shfl_xor(mnx, 32)); mny = fminf(mny, __shfl_xor(mny, 32));
            float invD = 1.f / (sw + 1e-16f);
            float dc = (float)(deg > 0 ? deg : 1);
            float meanx = sx * invD / dc, meany = sy * invD / dc;
            float sqmx = qx * invD * invD / dc, sqmy = qy * invD * invD / dc;
            float stdx = sqrtf(fmaxf(sqmx - meanx * meanx, 0.f) + 1e-12f);
            float stdy = sqrtf(fmaxf(sqmy - meany * meany, 0.f) + 1e-12f);
            ushort2* row = (ushort2*)&scat[j * 264];
            if (half == 0) {
                ushort2 a; a.x = f2bf(meanx); a.y = f2bf(meany);
                row[c2] = a;
                ushort2 bmax; bmax.x = f2bf(deg > 0 ? mxx * invD : 0.f);
                bmax.y = f2bf(deg > 0 ? mxy * invD : 0.f);
                row[32 + c2] = bmax;
            } else {
                ushort2 bmin; bmin.x = f2bf(deg > 0 ? mnx * invD : 0.f);
                bmin.y = f2bf(deg > 0 ? mny * invD : 0.f);
                row[64 + c2] = bmin;
                ushort2 bstd; bstd.x = f2bf(stdx); bstd.y = f2bf(stdy);
                row[96 + c2] = bstd;
            }
        }
        __syncthreads();
        f32x4 acc = {0.f, 0.f, 0.f, 0.f};
        #pragma unroll
        for (int s = 0; s < 8; s++) {
            bf16x8 a = *(const bf16x8*)&scat[nn * 264 + 32 * s + quad * 8];
            acc = __builtin_amdgcn_mfma_f32_16x16x32_bf16(a, wfrag[s], acc, 0, 0, 0);
        }
        int4 mc4 = *(const int4*)&mcount[base + 4 * quad];
        float h0 = lrelu(acc[0] + bias);
        float h1 = lrelu(acc[1] + bias);
        float h2 = lrelu(acc[2] + bias);
        float h3 = lrelu(acc[3] + bias);
        pool += h0 + h1 + h2 + h3;
        pmac += (float)mc4.x * h0 + (float)mc4.y * h1 + (float)mc4.z * h2 + (float)mc4.w * h3;
    }
    pool += __shfl_xor(pool, 16); pool += __shfl_xor(pool, 32);
    pmac += __shfl_xor(pmac, 16); pmac += __shfl_xor(pmac, 32);
    if (quad == 0) {
        atomicAdd(&sum_all[wave * 16 + nn], pool);
        atomicAdd(&sum_mac[wave * 16 + nn], pmac);
    }
}

// ---------- tiny MLP head ----------
__global__ __launch_bounds__(256) void k_final(
    const float* __restrict__ sum_all, const float* __restrict__ sum_mac,
    const float* __restrict__ Wm1, const float* __restrict__ bm1,
    const float* __restrict__ Wm2, const float* __restrict__ bm2,
    const float* __restrict__ Wm3, const float* __restrict__ bm3,
    float* __restrict__ out)
{
    __shared__ float spool[128];
    __shared__ float z1[64];
    __shared__ float z2[32];
    if (threadIdx.x < 64) {
        spool[threadIdx.x]      = sum_mac[threadIdx.x] / (float)N_MACRO;
        spool[64 + threadIdx.x] = sum_all[threadIdx.x] / (float)N_NODES;
    }
    __syncthreads();
    if (threadIdx.x < 64) {
        int j = threadIdx.x;
        float a = bm1[j];
        #pragma unroll 4
        for (int k = 0; k < 128; k++) a += spool[k] * Wm1[k * 64 + j];
        z1[j] = lrelu(a);
    }
    __syncthreads();
    if (threadIdx.x < 32) {
        int j = threadIdx.x;
        float a = bm2[j];
        #pragma unroll 4
        for (int k = 0; k < 64; k++) a += z1[k] * Wm2[k * 32 + j];
        z2[j] = lrelu(a);
    }
    __syncthreads();
    if (threadIdx.x == 0) {
        float a = bm3[0];
        #pragma unroll
        for (int k = 0; k < 32; k++) a += z2[k] * Wm3[k];
        out[0] = a;
    }
}

// ---------- launch ----------
extern "C" void kernel_launch(void* const* d_in, const int* in_sizes, int n_in,
                              void* d_out, int out_size, void* d_ws, size_t ws_size,
                              hipStream_t stream)
{
    const float* x        = (const float*)d_in[0];
    const float* fake_pos = (const float*)d_in[1];
    const int*   edge     = (const int*)d_in[2];
    const float* pinf     = (const float*)d_in[3];
    const int*   macro    = (const int*)d_in[4];
    const float* W1    = (const float*)d_in[5];
    const float* b1    = (const float*)d_in[6];
    const float* Wpin  = (const float*)d_in[7];
    const float* att   = (const float*)d_in[8];
    const float* Wpost = (const float*)d_in[9];
    const float* bpost = (const float*)d_in[10];
    const float* Wm1   = (const float*)d_in[11];
    const float* bm1   = (const float*)d_in[12];
    const float* Wm2   = (const float*)d_in[13];
    const float* bm2   = (const float*)d_in[14];
    const float* Wm3   = (const float*)d_in[15];
    const float* bm3   = (const float*)d_in[16];
    float* out = (float*)d_out;

    float* ws = (float*)d_ws;
    // layout (4-byte units); zero region = [0, 700128)
    float*    ismacro = ws;                         //   200,000
    float*    sum_all = ws + 200000;                //        64
    float*    sum_mac = ws + 200064;                //        64
    int*      mcount  = (int*)(ws + 200128);        //   200,000
    int*      cnt     = (int*)(ws + 400128);        //   300,000
    // end zero region (700,128)
    int*      row_ptr  = (int*)(ws + 700128);       //   300,001
    int*      partials = (int*)(ws + 1000132);      //       300
    float*    va       = ws + 1000432;              //        40
    int*      rank_n   = (int*)(ws + 1000472);      // 1,000,000
    int*      rank_e   = (int*)(ws + 2000472);      // 1,000,000
    int*      csr_n    = (int*)(ws + 3000472);      // 1,000,000 (node side: he ids)
    int4*     rec      = (int4*)(ws + 4000472);     // 1M x 16B = 4,000,000 units (16B-aligned)
    float*    e_att    = ws + 8000472;              //   100,000
    float*    xn_att   = ws + 8100472;              //   200,000
    unsigned short* h      = (unsigned short*)(ws + 8300472);  // 6.4M ushort (3.2M units)
    unsigned short* e_feat = (unsigned short*)(ws + 11500472); // 6.4M ushort (3.2M units)
    // total: 14,700,472 units ~= 58.8 MB

    const int* nidx = edge;
    const int* hidx = edge + NNZ;

    fill_f32<<<1024, 256, 0, stream>>>(ws, 700128LL, 0.f);
    k_pre<<<2051, 256, 0, stream>>>(macro, ismacro, mcount, W1, b1, att, va,
                                    nidx, hidx, cnt, rank_n, rank_e);
    k_scan1<<<NB_SCAN, 256, 0, stream>>>(cnt, row_ptr, partials);
    k_scan2<<<1, 512, 0, stream>>>(partials);
    k_scan3<<<NB_SCAN, 256, 0, stream>>>(row_ptr, partials);
    k_mid<<<3072, 256, 0, stream>>>(nidx, hidx, row_ptr, rank_n, rank_e,
                                    (const float4*)pinf, csr_n, rec,
                                    x, fake_pos, ismacro, va, h, xn_att);
    k_he_agg<<<2048, 256, 0, stream>>>(row_ptr, rec, W1, Wpin, b1, att, h, e_feat, e_att);
    k_fused<<<2048, 256, 0, stream>>>(row_ptr, csr_n, xn_att, e_att, e_feat, Wpost, bpost,
                                      mcount, sum_all, sum_mac);
    k_final<<<1, 256, 0, stream>>>(sum_all, sum_mac, Wm1, bm1, Wm2, bm2, Wm3, bm3, out);
}